// Round 17
// baseline (237.325 us; speedup 1.0000x reference)
//
#include <hip/hip_runtime.h>
#include <hip/hip_bf16.h>

#define S_SEQ 2048
#define R_RES 384
#define CIN   64
#define HC    64
#define NH    8
#define CHD   8

using bf16x8 = __attribute__((ext_vector_type(8))) short;
using f32x4  = __attribute__((ext_vector_type(4))) float;

__device__ __forceinline__ short f2bf(float v) {
  __hip_bfloat16 h = __float2bfloat16(v);
  union { __hip_bfloat16 b; short s; } u; u.b = h; return u.s;
}
__device__ __forceinline__ float bf2f(short s) {
  union { short s; __hip_bfloat16 b; } u; u.s = s; return __bfloat162float(u.b);
}

// ---------------------------------------------------------------------------
// Kernel 0: prep weight tables. (R15 verbatim)
// ---------------------------------------------------------------------------
__global__ __launch_bounds__(256) void k0_prep(
    const float* __restrict__ wg, const float* __restrict__ wo,
    const float* __restrict__ wk, const float* __restrict__ wv,
    const float* __restrict__ ln_w, const float* __restrict__ ln_b,
    short* __restrict__ wgT_hi, short* __restrict__ wgT_lo,
    short* __restrict__ woT_hi, short* __restrict__ woT_lo,
    short* __restrict__ wkvT_hi, short* __restrict__ wkvT_lo,
    float* __restrict__ bkv) {
  const int idx = blockIdx.x * 256 + threadIdx.x;
  if (idx < 16) {
    float s = 0.f;
    for (int c = 0; c < CIN; ++c)
      s += ln_b[c] * ((idx < 8) ? wk[c * CHD + idx] : wv[c * CHD + (idx - 8)]);
    bkv[idx] = s;
  }
  if (idx < 16 * CIN) {  // wkvT (folded)
    const int a = idx >> 6, c = idx & 63;
    const float w = ln_w[c] * ((a < 8) ? wk[c * CHD + a] : wv[c * CHD + (a - 8)]);
    short h = f2bf(w);
    wkvT_hi[idx] = h; wkvT_lo[idx] = f2bf(w - bf2f(h));
  }
  if (idx >= HC * CIN) return;
  const int a = idx >> 6;   // out row
  const int b = idx & 63;   // out col
  const float g = wg[b * HC + a];
  short gh = f2bf(g);
  wgT_hi[idx] = gh; wgT_lo[idx] = f2bf(g - bf2f(gh));
  const float o = wo[b * CIN + a];
  short oh = f2bf(o);
  woT_hi[idx] = oh; woT_lo[idx] = f2bf(o - bf2f(oh));
}

// ---------------------------------------------------------------------------
// Kernel 1 (MFMA): LN + K/V projection + masked pooled sums.
// R15 body (no unroll — R16 showed it neutral). NEW: if RS, store
// float2(mean, rstd) per row for k3 to reuse (bitwise-identical stats).
// ---------------------------------------------------------------------------
template <bool RS>
__global__ __launch_bounds__(256) void k1_mfma(
    const float* __restrict__ m, const float* __restrict__ mask,
    const short* __restrict__ wkvT_hi, const short* __restrict__ wkvT_lo,
    const float* __restrict__ bkv,
    float* __restrict__ Kd, float* __restrict__ Vd,
    float* __restrict__ qpool_part, float* __restrict__ qm_part,
    float2* __restrict__ rowstats) {
  const int r = blockIdx.x;
  const int chunk = blockIdx.y;  // 0..3
  const int tid = threadIdx.x;
  const int wave = tid >> 6;
  const int lane = tid & 63;
  const int lrow = lane & 15;
  const int lpart = lane >> 4;
  const int s_base = chunk * 512 + wave * 128;

  __shared__ float redA[4][CIN];
  __shared__ float redM[4];

  bf16x8 kvh[2], kvl[2];
  #pragma unroll
  for (int k = 0; k < 2; ++k) {
    const int idx = lrow * 64 + k * 32 + lpart * 8;
    kvh[k] = *reinterpret_cast<const bf16x8*>(wkvT_hi + idx);
    kvl[k] = *reinterpret_cast<const bf16x8*>(wkvT_lo + idx);
  }
  const float4 bkvq = *reinterpret_cast<const float4*>(bkv + lpart * 4);

  float qacc[16];
  #pragma unroll
  for (int e = 0; e < 16; ++e) qacc[e] = 0.f;
  float macc = 0.f;

  for (int t = 0; t < 8; ++t) {
    const int srow = s_base + t * 16 + lrow;
    const float* mrow = m + ((size_t)srow * R_RES + r) * CIN;
    float x0[8], x1[8];
    {
      const float4* p0 = reinterpret_cast<const float4*>(mrow + lpart * 8);
      const float4* p1 = reinterpret_cast<const float4*>(mrow + 32 + lpart * 8);
      float4 a = p0[0], b = p0[1], c = p1[0], d = p1[1];
      x0[0]=a.x; x0[1]=a.y; x0[2]=a.z; x0[3]=a.w; x0[4]=b.x; x0[5]=b.y; x0[6]=b.z; x0[7]=b.w;
      x1[0]=c.x; x1[1]=c.y; x1[2]=c.z; x1[3]=c.w; x1[4]=d.x; x1[5]=d.y; x1[6]=d.z; x1[7]=d.w;
    }
    const float mk = mask[(size_t)srow * R_RES + r];

    float s = 0.f;
    #pragma unroll
    for (int e = 0; e < 8; ++e) s += x0[e] + x1[e];
    s += __shfl_xor(s, 16, 64);
    s += __shfl_xor(s, 32, 64);
    const float mean = s * (1.0f / CIN);
    float vs = 0.f;
    #pragma unroll
    for (int e = 0; e < 8; ++e) {
      float d0 = x0[e] - mean, d1 = x1[e] - mean;
      vs += d0 * d0 + d1 * d1;
    }
    vs += __shfl_xor(vs, 16, 64);
    vs += __shfl_xor(vs, 32, 64);
    const float rstd = rsqrtf(vs * (1.0f / CIN) + 1e-5f);

    if constexpr (RS) {
      if (lpart == 0)
        rowstats[(size_t)srow * R_RES + r] = make_float2(mean, rstd);
    }

    bf16x8 ah0, al0, ah1, al1;
    #pragma unroll
    for (int e = 0; e < 8; ++e) {
      const float xh0 = (x0[e] - mean) * rstd;
      const float xh1 = (x1[e] - mean) * rstd;
      qacc[e]     += mk * xh0;
      qacc[8 + e] += mk * xh1;
      short h = f2bf(xh0);
      ah0[e] = h; al0[e] = f2bf(xh0 - bf2f(h));
      h = f2bf(xh1);
      ah1[e] = h; al1[e] = f2bf(xh1 - bf2f(h));
    }
    macc += mk;

    f32x4 a = {0.f, 0.f, 0.f, 0.f};
    a = __builtin_amdgcn_mfma_f32_16x16x32_bf16(kvh[0], ah0, a, 0, 0, 0);
    a = __builtin_amdgcn_mfma_f32_16x16x32_bf16(kvh[1], ah1, a, 0, 0, 0);
    a = __builtin_amdgcn_mfma_f32_16x16x32_bf16(kvl[0], ah0, a, 0, 0, 0);
    a = __builtin_amdgcn_mfma_f32_16x16x32_bf16(kvl[1], ah1, a, 0, 0, 0);
    a = __builtin_amdgcn_mfma_f32_16x16x32_bf16(kvh[0], al0, a, 0, 0, 0);
    a = __builtin_amdgcn_mfma_f32_16x16x32_bf16(kvh[1], al1, a, 0, 0, 0);

    const size_t off = ((size_t)r * S_SEQ + srow) * CHD + (lpart & 1) * 4;
    float* dst = ((lpart & 2) ? Vd : Kd) + off;
    *reinterpret_cast<float4*>(dst) =
        make_float4(a[0] + bkvq.x, a[1] + bkvq.y, a[2] + bkvq.z, a[3] + bkvq.w);
  }

  #pragma unroll
  for (int off = 1; off <= 8; off <<= 1) {
    #pragma unroll
    for (int e = 0; e < 16; ++e) qacc[e] += __shfl_xor(qacc[e], off, 64);
    macc += __shfl_xor(macc, off, 64);
  }
  if (lrow == 0) {
    #pragma unroll
    for (int e = 0; e < 8; ++e) {
      redA[wave][lpart * 8 + e] = qacc[e];
      redA[wave][32 + lpart * 8 + e] = qacc[8 + e];
    }
    if (lpart == 0) redM[wave] = macc;
  }
  __syncthreads();
  if (tid < CIN) {
    const float tot = redA[0][tid] + redA[1][tid] + redA[2][tid] + redA[3][tid];
    qpool_part[((size_t)chunk * R_RES + r) * CIN + tid] = tot;
  }
  if (tid == 0)
    qm_part[chunk * R_RES + r] = redM[0] + redM[1] + redM[2] + redM[3];
}

// ---------------------------------------------------------------------------
// Kernel 2: per-residue global attention — single-pass online softmax.
// (R13/R15 verbatim.)
// ---------------------------------------------------------------------------
__global__ __launch_bounds__(256) void k2_attn(
    const float* __restrict__ mask,
    const float* __restrict__ ln_w, const float* __restrict__ ln_b,
    const float* __restrict__ wq,
    const float* __restrict__ qpool_part, const float* __restrict__ qm_part,
    const float* __restrict__ Kd, const float* __restrict__ Vd,
    float* __restrict__ od) {
  const int r = blockIdx.x;
  const int tid = threadIdx.x;
  const int lane = tid & 63;
  const int wave = tid >> 6;

  __shared__ float s_q[HC];
  __shared__ float s_qp[CIN];
  __shared__ float redw[4][CIN];
  __shared__ float dred[4][NH];
  __shared__ float mred[4][NH];

  const float msum_tot = qm_part[0 * R_RES + r] + qm_part[1 * R_RES + r] +
                         qm_part[2 * R_RES + r] + qm_part[3 * R_RES + r];

  if (tid < CIN) {
    float A = 0.f;
    #pragma unroll
    for (int ch = 0; ch < 4; ++ch)
      A += qpool_part[((size_t)ch * R_RES + r) * CIN + tid];
    s_qp[tid] = (ln_w[tid] * A + ln_b[tid] * msum_tot) / (msum_tot + 1e-10f);
  }
  __syncthreads();
  if (tid < HC) {
    float qj = 0.f;
    for (int c = 0; c < CIN; ++c) qj += s_qp[c] * wq[c * HC + tid];
    s_q[tid] = qj * 0.35355339059327373f;  // 1/sqrt(8)
  }
  __syncthreads();

  float mh[NH], dp[NH];
  #pragma unroll
  for (int h = 0; h < NH; ++h) { mh[h] = -1e30f; dp[h] = 0.f; }
  float opart[HC];
  #pragma unroll
  for (int i = 0; i < HC; ++i) opart[i] = 0.f;

  for (int s = tid; s < S_SEQ; s += 256) {
    float kk[CHD], vv[CHD];
    const float4* kp = reinterpret_cast<const float4*>(Kd + ((size_t)r * S_SEQ + s) * CHD);
    const float4* vp = reinterpret_cast<const float4*>(Vd + ((size_t)r * S_SEQ + s) * CHD);
    float4 a = kp[0], b = kp[1], c4 = vp[0], d4 = vp[1];
    kk[0] = a.x; kk[1] = a.y; kk[2] = a.z; kk[3] = a.w;
    kk[4] = b.x; kk[5] = b.y; kk[6] = b.z; kk[7] = b.w;
    vv[0] = c4.x; vv[1] = c4.y; vv[2] = c4.z; vv[3] = c4.w;
    vv[4] = d4.x; vv[5] = d4.y; vv[6] = d4.z; vv[7] = d4.w;
    const float madd = 1e9f * (mask[(size_t)s * R_RES + r] - 1.0f);
    #pragma unroll
    for (int h = 0; h < NH; ++h) {
      float l = madd;
      #pragma unroll
      for (int j = 0; j < CHD; ++j) l += s_q[h * CHD + j] * kk[j];
      const float newm = fmaxf(mh[h], l);
      const float sc = __expf(mh[h] - newm);
      const float p  = __expf(l - newm);
      dp[h] = dp[h] * sc + p;
      #pragma unroll
      for (int j = 0; j < CHD; ++j)
        opart[h * CHD + j] = opart[h * CHD + j] * sc + p * vv[j];
      mh[h] = newm;
    }
  }

  float wm[NH];
  #pragma unroll
  for (int h = 0; h < NH; ++h) {
    wm[h] = mh[h];
    #pragma unroll
    for (int off = 32; off >= 1; off >>= 1)
      wm[h] = fmaxf(wm[h], __shfl_xor(wm[h], off, 64));
  }
  if (lane == 0) {
    #pragma unroll
    for (int h = 0; h < NH; ++h) mred[wave][h] = wm[h];
  }
  __syncthreads();
  #pragma unroll
  for (int h = 0; h < NH; ++h)
    wm[h] = fmaxf(fmaxf(mred[0][h], mred[1][h]), fmaxf(mred[2][h], mred[3][h]));

  #pragma unroll
  for (int h = 0; h < NH; ++h) {
    const float sc = __expf(mh[h] - wm[h]);
    dp[h] *= sc;
    #pragma unroll
    for (int j = 0; j < CHD; ++j) opart[h * CHD + j] *= sc;
  }

  #pragma unroll
  for (int h = 0; h < NH; ++h) {
    float v = dp[h];
    #pragma unroll
    for (int off = 32; off >= 1; off >>= 1) v += __shfl_xor(v, off, 64);
    dp[h] = v;
  }
  if (lane == 0) {
    #pragma unroll
    for (int h = 0; h < NH; ++h) dred[wave][h] = dp[h];
  }
  float keep = 0.f;
  #pragma unroll
  for (int c = 0; c < HC; ++c) {
    float val = opart[c];
    #pragma unroll
    for (int off = 32; off >= 1; off >>= 1) val += __shfl_xor(val, off, 64);
    if (lane == c) keep = val;
  }
  redw[wave][lane] = keep;
  __syncthreads();
  if (tid < HC) {
    const float tot = redw[0][tid] + redw[1][tid] + redw[2][tid] + redw[3][tid];
    const int h = tid >> 3;
    const float den = dred[0][h] + dred[1][h] + dred[2][h] + dred[3][h];
    od[(size_t)r * HC + tid] = tot / den;
  }
}

// ---------------------------------------------------------------------------
// Kernel 3 (MFMA): round-9 kernel; if RS, LN stats loaded from rowstats
// (computed identically in k1) instead of recomputed — deletes the serial
// shuffle/VALU stats chain from pass 1's critical path.
// ---------------------------------------------------------------------------
template <bool RS>
__global__ __launch_bounds__(128) void k3_mfma(
    const float* __restrict__ m,
    const float* __restrict__ ln_w, const float* __restrict__ ln_b,
    const short* __restrict__ wgT_hi, const short* __restrict__ wgT_lo,
    const short* __restrict__ woT_hi, const short* __restrict__ woT_lo,
    const float* __restrict__ bg, const float* __restrict__ bo,
    const float* __restrict__ od, const float2* __restrict__ rowstats,
    float* __restrict__ out) {
  const int tid = threadIdx.x;
  const int wave = tid >> 6;
  const int lane = tid & 63;
  const int lrow = lane & 15;   // A/B frag row index
  const int lpart = lane >> 4;  // 0..3, k-chunk owner
  const size_t base = (size_t)blockIdx.x * 128 + (size_t)wave * 64;
  const int base_r = (int)(base % R_RES);

  __shared__ float t_lds[2][64 * 64];  // per-wave t tile, XOR-swizzled rows
  float* tw = t_lds[wave];

  float bgv[4], bov[4];
  #pragma unroll
  for (int n = 0; n < 4; ++n) { bgv[n] = bg[n * 16 + lrow]; bov[n] = bo[n * 16 + lrow]; }

  float lw0[8], lb0[8], lw1[8], lb1[8];
  {
    const float4* w0 = reinterpret_cast<const float4*>(ln_w + lpart * 8);
    const float4* w1 = reinterpret_cast<const float4*>(ln_w + 32 + lpart * 8);
    const float4* b0 = reinterpret_cast<const float4*>(ln_b + lpart * 8);
    const float4* b1 = reinterpret_cast<const float4*>(ln_b + 32 + lpart * 8);
    float4 a = w0[0], b = w0[1], c = w1[0], d = w1[1];
    lw0[0]=a.x; lw0[1]=a.y; lw0[2]=a.z; lw0[3]=a.w; lw0[4]=b.x; lw0[5]=b.y; lw0[6]=b.z; lw0[7]=b.w;
    lw1[0]=c.x; lw1[1]=c.y; lw1[2]=c.z; lw1[3]=c.w; lw1[4]=d.x; lw1[5]=d.y; lw1[6]=d.z; lw1[7]=d.w;
    a = b0[0]; b = b0[1]; c = b1[0]; d = b1[1];
    lb0[0]=a.x; lb0[1]=a.y; lb0[2]=a.z; lb0[3]=a.w; lb0[4]=b.x; lb0[5]=b.y; lb0[6]=b.z; lb0[7]=b.w;
    lb1[0]=c.x; lb1[1]=c.y; lb1[2]=c.z; lb1[3]=c.w; lb1[4]=d.x; lb1[5]=d.y; lb1[6]=d.z; lb1[7]=d.w;
  }

  // ---- B1 frags (wgT hi/lo)
  bf16x8 b1h[4][2], b1l[4][2];
  #pragma unroll
  for (int n = 0; n < 4; ++n) {
    #pragma unroll
    for (int k = 0; k < 2; ++k) {
      const int idx = (n * 16 + lrow) * 64 + k * 32 + lpart * 8;
      b1h[n][k] = *reinterpret_cast<const bf16x8*>(wgT_hi + idx);
      b1l[n][k] = *reinterpret_cast<const bf16x8*>(wgT_lo + idx);
    }
  }

  // ---- Pass 1: LN -> GEMM1 -> sigmoid*o -> t to LDS ----
  #pragma unroll
  for (int mt = 0; mt < 4; ++mt) {
    const size_t grow = base + mt * 16 + lrow;
    const float* mrow = m + grow * CIN;

    float mean, rstd;
    float x0[8], x1[8];
    if constexpr (RS) {
      const float2 st = rowstats[grow];  // independent load, hoistable
      const float4* p0 = reinterpret_cast<const float4*>(mrow + lpart * 8);
      const float4* p1 = reinterpret_cast<const float4*>(mrow + 32 + lpart * 8);
      float4 a = p0[0], b = p0[1], c = p1[0], d = p1[1];
      x0[0]=a.x; x0[1]=a.y; x0[2]=a.z; x0[3]=a.w; x0[4]=b.x; x0[5]=b.y; x0[6]=b.z; x0[7]=b.w;
      x1[0]=c.x; x1[1]=c.y; x1[2]=c.z; x1[3]=c.w; x1[4]=d.x; x1[5]=d.y; x1[6]=d.z; x1[7]=d.w;
      mean = st.x; rstd = st.y;
    } else {
      const float4* p0 = reinterpret_cast<const float4*>(mrow + lpart * 8);
      const float4* p1 = reinterpret_cast<const float4*>(mrow + 32 + lpart * 8);
      float4 a = p0[0], b = p0[1], c = p1[0], d = p1[1];
      x0[0]=a.x; x0[1]=a.y; x0[2]=a.z; x0[3]=a.w; x0[4]=b.x; x0[5]=b.y; x0[6]=b.z; x0[7]=b.w;
      x1[0]=c.x; x1[1]=c.y; x1[2]=c.z; x1[3]=c.w; x1[4]=d.x; x1[5]=d.y; x1[6]=d.z; x1[7]=d.w;
      float s = 0.f;
      #pragma unroll
      for (int e = 0; e < 8; ++e) s += x0[e] + x1[e];
      s += __shfl_xor(s, 16, 64);
      s += __shfl_xor(s, 32, 64);
      mean = s * (1.0f / CIN);
      float vs = 0.f;
      #pragma unroll
      for (int e = 0; e < 8; ++e) {
        float d0 = x0[e] - mean, d1 = x1[e] - mean;
        vs += d0 * d0 + d1 * d1;
      }
      vs += __shfl_xor(vs, 16, 64);
      vs += __shfl_xor(vs, 32, 64);
      rstd = rsqrtf(vs * (1.0f / CIN) + 1e-5f);
    }

    bf16x8 ah0, al0, ah1, al1;
    #pragma unroll
    for (int e = 0; e < 8; ++e) {
      float xn = (x0[e] - mean) * rstd * lw0[e] + lb0[e];
      short h = f2bf(xn);
      ah0[e] = h; al0[e] = f2bf(xn - bf2f(h));
      xn = (x1[e] - mean) * rstd * lw1[e] + lb1[e];
      h = f2bf(xn);
      ah1[e] = h; al1[e] = f2bf(xn - bf2f(h));
    }

    #pragma unroll
    for (int n = 0; n < 4; ++n) {
      f32x4 acc = {0.f, 0.f, 0.f, 0.f};
      acc = __builtin_amdgcn_mfma_f32_16x16x32_bf16(ah0, b1h[n][0], acc, 0, 0, 0);
      acc = __builtin_amdgcn_mfma_f32_16x16x32_bf16(ah1, b1h[n][1], acc, 0, 0, 0);
      acc = __builtin_amdgcn_mfma_f32_16x16x32_bf16(ah0, b1l[n][0], acc, 0, 0, 0);
      acc = __builtin_amdgcn_mfma_f32_16x16x32_bf16(ah1, b1l[n][1], acc, 0, 0, 0);
      acc = __builtin_amdgcn_mfma_f32_16x16x32_bf16(al0, b1h[n][0], acc, 0, 0, 0);
      acc = __builtin_amdgcn_mfma_f32_16x16x32_bf16(al1, b1h[n][1], acc, 0, 0, 0);
      const int j = n * 16 + lrow;
      #pragma unroll
      for (int i = 0; i < 4; ++i) {
        const int rl = mt * 16 + lpart * 4 + i;
        int r = base_r + rl; if (r >= R_RES) r -= R_RES;
        const float z = acc[i] + bgv[n];
        const float g = 1.0f / (1.0f + __expf(-z));
        const float t = g * od[(size_t)r * HC + j];
        const int off = ((rl * 256 + j * 4)) ^ ((rl & 7) << 4);
        *reinterpret_cast<float*>(reinterpret_cast<char*>(tw) + off) = t;
      }
    }
  }

  __syncthreads();  // safe ordering of LDS writes -> reads (also within wave)

  // ---- B2 frags (woT hi/lo) replace B1 ----
  bf16x8 b2h[4][2], b2l[4][2];
  #pragma unroll
  for (int n = 0; n < 4; ++n) {
    #pragma unroll
    for (int k = 0; k < 2; ++k) {
      const int idx = (n * 16 + lrow) * 64 + k * 32 + lpart * 8;
      b2h[n][k] = *reinterpret_cast<const bf16x8*>(woT_hi + idx);
      b2l[n][k] = *reinterpret_cast<const bf16x8*>(woT_lo + idx);
    }
  }

  // ---- Pass 2: t -> GEMM2 -> out ----
  #pragma unroll
  for (int mt = 0; mt < 4; ++mt) {
    const int rl2 = mt * 16 + lrow;
    const int swz = (rl2 & 7) << 4;
    bf16x8 ah0, al0, ah1, al1;
    {
      const int a0 = rl2 * 256 + lpart * 32;         // k-chunk 0: j = lpart*8..
      const int a1 = rl2 * 256 + 128 + lpart * 32;   // k-chunk 1: j = 32+lpart*8..
      char* tb = reinterpret_cast<char*>(tw);
      float4 u0 = *reinterpret_cast<float4*>(tb + (a0 ^ swz));
      float4 u1 = *reinterpret_cast<float4*>(tb + ((a0 + 16) ^ swz));
      float4 u2 = *reinterpret_cast<float4*>(tb + (a1 ^ swz));
      float4 u3 = *reinterpret_cast<float4*>(tb + ((a1 + 16) ^ swz));
      float t0[8] = {u0.x, u0.y, u0.z, u0.w, u1.x, u1.y, u1.z, u1.w};
      float t1[8] = {u2.x, u2.y, u2.z, u2.w, u3.x, u3.y, u3.z, u3.w};
      #pragma unroll
      for (int e = 0; e < 8; ++e) {
        short h = f2bf(t0[e]);
        ah0[e] = h; al0[e] = f2bf(t0[e] - bf2f(h));
        h = f2bf(t1[e]);
        ah1[e] = h; al1[e] = f2bf(t1[e] - bf2f(h));
      }
    }
    #pragma unroll
    for (int n = 0; n < 4; ++n) {
      f32x4 acc = {0.f, 0.f, 0.f, 0.f};
      acc = __builtin_amdgcn_mfma_f32_16x16x32_bf16(ah0, b2h[n][0], acc, 0, 0, 0);
      acc = __builtin_amdgcn_mfma_f32_16x16x32_bf16(ah1, b2h[n][1], acc, 0, 0, 0);
      acc = __builtin_amdgcn_mfma_f32_16x16x32_bf16(ah0, b2l[n][0], acc, 0, 0, 0);
      acc = __builtin_amdgcn_mfma_f32_16x16x32_bf16(ah1, b2l[n][1], acc, 0, 0, 0);
      acc = __builtin_amdgcn_mfma_f32_16x16x32_bf16(al0, b2h[n][0], acc, 0, 0, 0);
      acc = __builtin_amdgcn_mfma_f32_16x16x32_bf16(al1, b2h[n][1], acc, 0, 0, 0);
      const int cc = n * 16 + lrow;
      #pragma unroll
      for (int i = 0; i < 4; ++i) {
        const size_t grow = base + mt * 16 + lpart * 4 + i;
        out[grow * CIN + cc] = acc[i] + bov[n];
      }
    }
  }
}

// ---------------------------------------------------------------------------
extern "C" void kernel_launch(void* const* d_in, const int* in_sizes, int n_in,
                              void* d_out, int out_size, void* d_ws, size_t ws_size,
                              hipStream_t stream) {
  const float* m    = (const float*)d_in[0];
  const float* mask = (const float*)d_in[1];
  const float* ln_w = (const float*)d_in[2];
  const float* ln_b = (const float*)d_in[3];
  const float* wq   = (const float*)d_in[4];
  const float* wk   = (const float*)d_in[5];
  const float* wv   = (const float*)d_in[6];
  const float* wg   = (const float*)d_in[7];
  const float* bg   = (const float*)d_in[8];
  const float* wo   = (const float*)d_in[9];
  const float* bo   = (const float*)d_in[10];
  float* out = (float*)d_out;

  const size_t sizeK   = (size_t)R_RES * S_SEQ * CHD * sizeof(float);   // 25.2 MB
  const size_t sizeQP  = (size_t)4 * R_RES * CIN * sizeof(float);       // 393 KB
  const size_t sizeQM  = (size_t)4 * R_RES * sizeof(float);
  const size_t sizeO   = (size_t)R_RES * HC * sizeof(float);
  const size_t sizeW   = (size_t)HC * CIN * sizeof(short);              // 8 KB
  const size_t sizeWKV = (size_t)16 * CIN * sizeof(short);              // 2 KB
  const size_t sizeRS  = (size_t)S_SEQ * R_RES * sizeof(float2);        // 6.3 MB

  char* ws = (char*)d_ws;
  float* Kd         = (float*)(ws);
  float* Vd         = (float*)(ws + sizeK);
  float* qpool_part = (float*)(ws + 2 * sizeK);
  float* qm_part    = (float*)(ws + 2 * sizeK + sizeQP);
  float* od         = (float*)(ws + 2 * sizeK + sizeQP + sizeQM);
  char* wbase       = ws + 2 * sizeK + sizeQP + sizeQM + sizeO;
  short* wgT_hi  = (short*)(wbase);
  short* wgT_lo  = (short*)(wbase + sizeW);
  short* woT_hi  = (short*)(wbase + 2 * sizeW);
  short* woT_lo  = (short*)(wbase + 3 * sizeW);
  short* wkvT_hi = (short*)(wbase + 4 * sizeW);
  short* wkvT_lo = (short*)(wbase + 4 * sizeW + sizeWKV);
  float* bkv     = (float*)(wbase + 4 * sizeW + 2 * sizeWKV);
  char* rsbase   = wbase + 4 * sizeW + 2 * sizeWKV + 256;  // after bkv (padded)
  float2* rowstats = (float2*)rsbase;

  const size_t needed_rs = (size_t)(rsbase - ws) + sizeRS;
  const bool use_rs = ws_size >= needed_rs;

  k0_prep<<<(HC * CIN + 255) / 256, 256, 0, stream>>>(
      wg, wo, wk, wv, ln_w, ln_b,
      wgT_hi, wgT_lo, woT_hi, woT_lo, wkvT_hi, wkvT_lo, bkv);

  if (use_rs) {
    k1_mfma<true><<<dim3(R_RES, 4), 256, 0, stream>>>(
        m, mask, wkvT_hi, wkvT_lo, bkv, Kd, Vd, qpool_part, qm_part, rowstats);
  } else {
    k1_mfma<false><<<dim3(R_RES, 4), 256, 0, stream>>>(
        m, mask, wkvT_hi, wkvT_lo, bkv, Kd, Vd, qpool_part, qm_part, nullptr);
  }

  k2_attn<<<R_RES, 256, 0, stream>>>(
      mask, ln_w, ln_b, wq, qpool_part, qm_part, Kd, Vd, od);

  if (use_rs) {
    k3_mfma<true><<<(S_SEQ * R_RES) / 128, 128, 0, stream>>>(
        m, ln_w, ln_b, wgT_hi, wgT_lo, woT_hi, woT_lo, bg, bo, od, rowstats, out);
  } else {
    k3_mfma<false><<<(S_SEQ * R_RES) / 128, 128, 0, stream>>>(
        m, ln_w, ln_b, wgT_hi, wgT_lo, woT_hi, woT_lo, bg, bo, od, nullptr, out);
  }
}

// Round 18
// 216.736 us; speedup vs baseline: 1.0950x; 1.0950x over previous
//
#include <hip/hip_runtime.h>
#include <hip/hip_bf16.h>

#define S_SEQ 2048
#define R_RES 384
#define CIN   64
#define HC    64
#define NH    8
#define CHD   8

using bf16x8 = __attribute__((ext_vector_type(8))) short;
using f32x4  = __attribute__((ext_vector_type(4))) float;

__device__ __forceinline__ short f2bf(float v) {
  __hip_bfloat16 h = __float2bfloat16(v);
  union { __hip_bfloat16 b; short s; } u; u.b = h; return u.s;
}
__device__ __forceinline__ float bf2f(short s) {
  union { short s; __hip_bfloat16 b; } u; u.s = s; return __bfloat162float(u.b);
}

// ---------------------------------------------------------------------------
// Kernel 0: prep weight tables. (R15 verbatim)
// wgT[j][c] = wg[c][j]; woT[cout][j] = wo[j][cout]  (hi/lo bf16, unfolded)
// wkvT[a][c] = ln_w[c]*[wk|wv][c][a&7] (hi/lo, folded)
// bkv[a] = sum_c ln_b[c]*[wk|wv][c][a&7]
// ---------------------------------------------------------------------------
__global__ __launch_bounds__(256) void k0_prep(
    const float* __restrict__ wg, const float* __restrict__ wo,
    const float* __restrict__ wk, const float* __restrict__ wv,
    const float* __restrict__ ln_w, const float* __restrict__ ln_b,
    short* __restrict__ wgT_hi, short* __restrict__ wgT_lo,
    short* __restrict__ woT_hi, short* __restrict__ woT_lo,
    short* __restrict__ wkvT_hi, short* __restrict__ wkvT_lo,
    float* __restrict__ bkv) {
  const int idx = blockIdx.x * 256 + threadIdx.x;
  if (idx < 16) {
    float s = 0.f;
    for (int c = 0; c < CIN; ++c)
      s += ln_b[c] * ((idx < 8) ? wk[c * CHD + idx] : wv[c * CHD + (idx - 8)]);
    bkv[idx] = s;
  }
  if (idx < 16 * CIN) {  // wkvT (folded)
    const int a = idx >> 6, c = idx & 63;
    const float w = ln_w[c] * ((a < 8) ? wk[c * CHD + a] : wv[c * CHD + (a - 8)]);
    short h = f2bf(w);
    wkvT_hi[idx] = h; wkvT_lo[idx] = f2bf(w - bf2f(h));
  }
  if (idx >= HC * CIN) return;
  const int a = idx >> 6;   // out row
  const int b = idx & 63;   // out col
  const float g = wg[b * HC + a];
  short gh = f2bf(g);
  wgT_hi[idx] = gh; wgT_lo[idx] = f2bf(g - bf2f(gh));
  const float o = wo[b * CIN + a];
  short oh = f2bf(o);
  woT_hi[idx] = oh; woT_lo[idx] = f2bf(o - bf2f(oh));
}

// ---------------------------------------------------------------------------
// Kernel 1 (MFMA): LN + K/V projection + masked pooled sums. (R15 verbatim:
// launch bound (256) — no min-waves cap, no unroll, no rowstats.)
// ---------------------------------------------------------------------------
__global__ __launch_bounds__(256) void k1_mfma(
    const float* __restrict__ m, const float* __restrict__ mask,
    const short* __restrict__ wkvT_hi, const short* __restrict__ wkvT_lo,
    const float* __restrict__ bkv,
    float* __restrict__ Kd, float* __restrict__ Vd,
    float* __restrict__ qpool_part, float* __restrict__ qm_part) {
  const int r = blockIdx.x;
  const int chunk = blockIdx.y;  // 0..3
  const int tid = threadIdx.x;
  const int wave = tid >> 6;
  const int lane = tid & 63;
  const int lrow = lane & 15;
  const int lpart = lane >> 4;
  const int s_base = chunk * 512 + wave * 128;

  __shared__ float redA[4][CIN];
  __shared__ float redM[4];

  bf16x8 kvh[2], kvl[2];
  #pragma unroll
  for (int k = 0; k < 2; ++k) {
    const int idx = lrow * 64 + k * 32 + lpart * 8;
    kvh[k] = *reinterpret_cast<const bf16x8*>(wkvT_hi + idx);
    kvl[k] = *reinterpret_cast<const bf16x8*>(wkvT_lo + idx);
  }
  const float4 bkvq = *reinterpret_cast<const float4*>(bkv + lpart * 4);

  float qacc[16];
  #pragma unroll
  for (int e = 0; e < 16; ++e) qacc[e] = 0.f;
  float macc = 0.f;

  for (int t = 0; t < 8; ++t) {
    const int srow = s_base + t * 16 + lrow;
    const float* mrow = m + ((size_t)srow * R_RES + r) * CIN;
    float x0[8], x1[8];
    {
      const float4* p0 = reinterpret_cast<const float4*>(mrow + lpart * 8);
      const float4* p1 = reinterpret_cast<const float4*>(mrow + 32 + lpart * 8);
      float4 a = p0[0], b = p0[1], c = p1[0], d = p1[1];
      x0[0]=a.x; x0[1]=a.y; x0[2]=a.z; x0[3]=a.w; x0[4]=b.x; x0[5]=b.y; x0[6]=b.z; x0[7]=b.w;
      x1[0]=c.x; x1[1]=c.y; x1[2]=c.z; x1[3]=c.w; x1[4]=d.x; x1[5]=d.y; x1[6]=d.z; x1[7]=d.w;
    }
    const float mk = mask[(size_t)srow * R_RES + r];

    float s = 0.f;
    #pragma unroll
    for (int e = 0; e < 8; ++e) s += x0[e] + x1[e];
    s += __shfl_xor(s, 16, 64);
    s += __shfl_xor(s, 32, 64);
    const float mean = s * (1.0f / CIN);
    float vs = 0.f;
    #pragma unroll
    for (int e = 0; e < 8; ++e) {
      float d0 = x0[e] - mean, d1 = x1[e] - mean;
      vs += d0 * d0 + d1 * d1;
    }
    vs += __shfl_xor(vs, 16, 64);
    vs += __shfl_xor(vs, 32, 64);
    const float rstd = rsqrtf(vs * (1.0f / CIN) + 1e-5f);

    bf16x8 ah0, al0, ah1, al1;
    #pragma unroll
    for (int e = 0; e < 8; ++e) {
      const float xh0 = (x0[e] - mean) * rstd;
      const float xh1 = (x1[e] - mean) * rstd;
      qacc[e]     += mk * xh0;
      qacc[8 + e] += mk * xh1;
      short h = f2bf(xh0);
      ah0[e] = h; al0[e] = f2bf(xh0 - bf2f(h));
      h = f2bf(xh1);
      ah1[e] = h; al1[e] = f2bf(xh1 - bf2f(h));
    }
    macc += mk;

    f32x4 a = {0.f, 0.f, 0.f, 0.f};
    a = __builtin_amdgcn_mfma_f32_16x16x32_bf16(kvh[0], ah0, a, 0, 0, 0);
    a = __builtin_amdgcn_mfma_f32_16x16x32_bf16(kvh[1], ah1, a, 0, 0, 0);
    a = __builtin_amdgcn_mfma_f32_16x16x32_bf16(kvl[0], ah0, a, 0, 0, 0);
    a = __builtin_amdgcn_mfma_f32_16x16x32_bf16(kvl[1], ah1, a, 0, 0, 0);
    a = __builtin_amdgcn_mfma_f32_16x16x32_bf16(kvh[0], al0, a, 0, 0, 0);
    a = __builtin_amdgcn_mfma_f32_16x16x32_bf16(kvh[1], al1, a, 0, 0, 0);

    const size_t off = ((size_t)r * S_SEQ + srow) * CHD + (lpart & 1) * 4;
    float* dst = ((lpart & 2) ? Vd : Kd) + off;
    *reinterpret_cast<float4*>(dst) =
        make_float4(a[0] + bkvq.x, a[1] + bkvq.y, a[2] + bkvq.z, a[3] + bkvq.w);
  }

  #pragma unroll
  for (int off = 1; off <= 8; off <<= 1) {
    #pragma unroll
    for (int e = 0; e < 16; ++e) qacc[e] += __shfl_xor(qacc[e], off, 64);
    macc += __shfl_xor(macc, off, 64);
  }
  if (lrow == 0) {
    #pragma unroll
    for (int e = 0; e < 8; ++e) {
      redA[wave][lpart * 8 + e] = qacc[e];
      redA[wave][32 + lpart * 8 + e] = qacc[8 + e];
    }
    if (lpart == 0) redM[wave] = macc;
  }
  __syncthreads();
  if (tid < CIN) {
    const float tot = redA[0][tid] + redA[1][tid] + redA[2][tid] + redA[3][tid];
    qpool_part[((size_t)chunk * R_RES + r) * CIN + tid] = tot;
  }
  if (tid == 0)
    qm_part[chunk * R_RES + r] = redM[0] + redM[1] + redM[2] + redM[3];
}

// ---------------------------------------------------------------------------
// Kernel 2: per-residue global attention — single-pass online softmax.
// (R13/R15 verbatim.)
// ---------------------------------------------------------------------------
__global__ __launch_bounds__(256) void k2_attn(
    const float* __restrict__ mask,
    const float* __restrict__ ln_w, const float* __restrict__ ln_b,
    const float* __restrict__ wq,
    const float* __restrict__ qpool_part, const float* __restrict__ qm_part,
    const float* __restrict__ Kd, const float* __restrict__ Vd,
    float* __restrict__ od) {
  const int r = blockIdx.x;
  const int tid = threadIdx.x;
  const int lane = tid & 63;
  const int wave = tid >> 6;

  __shared__ float s_q[HC];
  __shared__ float s_qp[CIN];
  __shared__ float redw[4][CIN];
  __shared__ float dred[4][NH];
  __shared__ float mred[4][NH];

  const float msum_tot = qm_part[0 * R_RES + r] + qm_part[1 * R_RES + r] +
                         qm_part[2 * R_RES + r] + qm_part[3 * R_RES + r];

  if (tid < CIN) {
    float A = 0.f;
    #pragma unroll
    for (int ch = 0; ch < 4; ++ch)
      A += qpool_part[((size_t)ch * R_RES + r) * CIN + tid];
    s_qp[tid] = (ln_w[tid] * A + ln_b[tid] * msum_tot) / (msum_tot + 1e-10f);
  }
  __syncthreads();
  if (tid < HC) {
    float qj = 0.f;
    for (int c = 0; c < CIN; ++c) qj += s_qp[c] * wq[c * HC + tid];
    s_q[tid] = qj * 0.35355339059327373f;  // 1/sqrt(8)
  }
  __syncthreads();

  // ---- single online pass over S ----
  float mh[NH], dp[NH];
  #pragma unroll
  for (int h = 0; h < NH; ++h) { mh[h] = -1e30f; dp[h] = 0.f; }
  float opart[HC];
  #pragma unroll
  for (int i = 0; i < HC; ++i) opart[i] = 0.f;

  for (int s = tid; s < S_SEQ; s += 256) {
    float kk[CHD], vv[CHD];
    const float4* kp = reinterpret_cast<const float4*>(Kd + ((size_t)r * S_SEQ + s) * CHD);
    const float4* vp = reinterpret_cast<const float4*>(Vd + ((size_t)r * S_SEQ + s) * CHD);
    float4 a = kp[0], b = kp[1], c4 = vp[0], d4 = vp[1];
    kk[0] = a.x; kk[1] = a.y; kk[2] = a.z; kk[3] = a.w;
    kk[4] = b.x; kk[5] = b.y; kk[6] = b.z; kk[7] = b.w;
    vv[0] = c4.x; vv[1] = c4.y; vv[2] = c4.z; vv[3] = c4.w;
    vv[4] = d4.x; vv[5] = d4.y; vv[6] = d4.z; vv[7] = d4.w;
    const float madd = 1e9f * (mask[(size_t)s * R_RES + r] - 1.0f);
    #pragma unroll
    for (int h = 0; h < NH; ++h) {
      float l = madd;
      #pragma unroll
      for (int j = 0; j < CHD; ++j) l += s_q[h * CHD + j] * kk[j];
      const float newm = fmaxf(mh[h], l);
      const float sc = __expf(mh[h] - newm);  // 1 if max unchanged
      const float p  = __expf(l - newm);
      dp[h] = dp[h] * sc + p;
      #pragma unroll
      for (int j = 0; j < CHD; ++j)
        opart[h * CHD + j] = opart[h * CHD + j] * sc + p * vv[j];
      mh[h] = newm;
    }
  }

  // ---- cross-lane/wave max ----
  float wm[NH];
  #pragma unroll
  for (int h = 0; h < NH; ++h) {
    wm[h] = mh[h];
    #pragma unroll
    for (int off = 32; off >= 1; off >>= 1)
      wm[h] = fmaxf(wm[h], __shfl_xor(wm[h], off, 64));
  }
  if (lane == 0) {
    #pragma unroll
    for (int h = 0; h < NH; ++h) mred[wave][h] = wm[h];
  }
  __syncthreads();
  #pragma unroll
  for (int h = 0; h < NH; ++h)
    wm[h] = fmaxf(fmaxf(mred[0][h], mred[1][h]), fmaxf(mred[2][h], mred[3][h]));

  // ---- rescale lane-local partials to global max (exact) ----
  #pragma unroll
  for (int h = 0; h < NH; ++h) {
    const float sc = __expf(mh[h] - wm[h]);
    dp[h] *= sc;
    #pragma unroll
    for (int j = 0; j < CHD; ++j) opart[h * CHD + j] *= sc;
  }

  // ---- reductions ----
  #pragma unroll
  for (int h = 0; h < NH; ++h) {
    float v = dp[h];
    #pragma unroll
    for (int off = 32; off >= 1; off >>= 1) v += __shfl_xor(v, off, 64);
    dp[h] = v;
  }
  if (lane == 0) {
    #pragma unroll
    for (int h = 0; h < NH; ++h) dred[wave][h] = dp[h];
  }
  float keep = 0.f;
  #pragma unroll
  for (int c = 0; c < HC; ++c) {
    float val = opart[c];
    #pragma unroll
    for (int off = 32; off >= 1; off >>= 1) val += __shfl_xor(val, off, 64);
    if (lane == c) keep = val;
  }
  redw[wave][lane] = keep;
  __syncthreads();
  if (tid < HC) {
    const float tot = redw[0][tid] + redw[1][tid] + redw[2][tid] + redw[3][tid];
    const int h = tid >> 3;
    const float den = dred[0][h] + dred[1][h] + dred[2][h] + dred[3][h];
    od[(size_t)r * HC + tid] = tot / den;
  }
}

// ---------------------------------------------------------------------------
// Kernel 3 (MFMA): EXACT round-9 kernel (measured 135 us). Do not edit.
// ---------------------------------------------------------------------------
__global__ __launch_bounds__(128) void k3_mfma(
    const float* __restrict__ m,
    const float* __restrict__ ln_w, const float* __restrict__ ln_b,
    const short* __restrict__ wgT_hi, const short* __restrict__ wgT_lo,
    const short* __restrict__ woT_hi, const short* __restrict__ woT_lo,
    const float* __restrict__ bg, const float* __restrict__ bo,
    const float* __restrict__ od, float* __restrict__ out) {
  const int tid = threadIdx.x;
  const int wave = tid >> 6;
  const int lane = tid & 63;
  const int lrow = lane & 15;   // A/B frag row index
  const int lpart = lane >> 4;  // 0..3, k-chunk owner
  const size_t base = (size_t)blockIdx.x * 128 + (size_t)wave * 64;
  const int base_r = (int)(base % R_RES);

  __shared__ float t_lds[2][64 * 64];  // per-wave t tile, XOR-swizzled rows
  float* tw = t_lds[wave];

  // per-lane bias values for columns j = n*16 + lrow
  float bgv[4], bov[4];
  #pragma unroll
  for (int n = 0; n < 4; ++n) { bgv[n] = bg[n * 16 + lrow]; bov[n] = bo[n * 16 + lrow]; }

  // LN params for this lane's two k-chunks: c = lpart*8+e and 32+lpart*8+e
  float lw0[8], lb0[8], lw1[8], lb1[8];
  {
    const float4* w0 = reinterpret_cast<const float4*>(ln_w + lpart * 8);
    const float4* w1 = reinterpret_cast<const float4*>(ln_w + 32 + lpart * 8);
    const float4* b0 = reinterpret_cast<const float4*>(ln_b + lpart * 8);
    const float4* b1 = reinterpret_cast<const float4*>(ln_b + 32 + lpart * 8);
    float4 a = w0[0], b = w0[1], c = w1[0], d = w1[1];
    lw0[0]=a.x; lw0[1]=a.y; lw0[2]=a.z; lw0[3]=a.w; lw0[4]=b.x; lw0[5]=b.y; lw0[6]=b.z; lw0[7]=b.w;
    lw1[0]=c.x; lw1[1]=c.y; lw1[2]=c.z; lw1[3]=c.w; lw1[4]=d.x; lw1[5]=d.y; lw1[6]=d.z; lw1[7]=d.w;
    a = b0[0]; b = b0[1]; c = b1[0]; d = b1[1];
    lb0[0]=a.x; lb0[1]=a.y; lb0[2]=a.z; lb0[3]=a.w; lb0[4]=b.x; lb0[5]=b.y; lb0[6]=b.z; lb0[7]=b.w;
    lb1[0]=c.x; lb1[1]=c.y; lb1[2]=c.z; lb1[3]=c.w; lb1[4]=d.x; lb1[5]=d.y; lb1[6]=d.z; lb1[7]=d.w;
  }

  // ---- B1 frags (wgT hi/lo): [n][k], lane reads wgT[n*16+lrow][k*32 + lpart*8 ..+7]
  bf16x8 b1h[4][2], b1l[4][2];
  #pragma unroll
  for (int n = 0; n < 4; ++n) {
    #pragma unroll
    for (int k = 0; k < 2; ++k) {
      const int idx = (n * 16 + lrow) * 64 + k * 32 + lpart * 8;
      b1h[n][k] = *reinterpret_cast<const bf16x8*>(wgT_hi + idx);
      b1l[n][k] = *reinterpret_cast<const bf16x8*>(wgT_lo + idx);
    }
  }

  // ---- Pass 1: LN -> GEMM1 -> sigmoid*o -> t to LDS ----
  #pragma unroll
  for (int mt = 0; mt < 4; ++mt) {
    const size_t grow = base + mt * 16 + lrow;
    const float* mrow = m + grow * CIN;
    float x0[8], x1[8];
    {
      const float4* p0 = reinterpret_cast<const float4*>(mrow + lpart * 8);
      const float4* p1 = reinterpret_cast<const float4*>(mrow + 32 + lpart * 8);
      float4 a = p0[0], b = p0[1], c = p1[0], d = p1[1];
      x0[0]=a.x; x0[1]=a.y; x0[2]=a.z; x0[3]=a.w; x0[4]=b.x; x0[5]=b.y; x0[6]=b.z; x0[7]=b.w;
      x1[0]=c.x; x1[1]=c.y; x1[2]=c.z; x1[3]=c.w; x1[4]=d.x; x1[5]=d.y; x1[6]=d.z; x1[7]=d.w;
    }
    float s = 0.f;
    #pragma unroll
    for (int e = 0; e < 8; ++e) s += x0[e] + x1[e];
    s += __shfl_xor(s, 16, 64);
    s += __shfl_xor(s, 32, 64);
    const float mean = s * (1.0f / CIN);
    float vs = 0.f;
    #pragma unroll
    for (int e = 0; e < 8; ++e) {
      float d0 = x0[e] - mean, d1 = x1[e] - mean;
      vs += d0 * d0 + d1 * d1;
    }
    vs += __shfl_xor(vs, 16, 64);
    vs += __shfl_xor(vs, 32, 64);
    const float rstd = rsqrtf(vs * (1.0f / CIN) + 1e-5f);

    bf16x8 ah0, al0, ah1, al1;
    #pragma unroll
    for (int e = 0; e < 8; ++e) {
      float xn = (x0[e] - mean) * rstd * lw0[e] + lb0[e];
      short h = f2bf(xn);
      ah0[e] = h; al0[e] = f2bf(xn - bf2f(h));
      xn = (x1[e] - mean) * rstd * lw1[e] + lb1[e];
      h = f2bf(xn);
      ah1[e] = h; al1[e] = f2bf(xn - bf2f(h));
    }

    #pragma unroll
    for (int n = 0; n < 4; ++n) {
      f32x4 acc = {0.f, 0.f, 0.f, 0.f};
      acc = __builtin_amdgcn_mfma_f32_16x16x32_bf16(ah0, b1h[n][0], acc, 0, 0, 0);
      acc = __builtin_amdgcn_mfma_f32_16x16x32_bf16(ah1, b1h[n][1], acc, 0, 0, 0);
      acc = __builtin_amdgcn_mfma_f32_16x16x32_bf16(ah0, b1l[n][0], acc, 0, 0, 0);
      acc = __builtin_amdgcn_mfma_f32_16x16x32_bf16(ah1, b1l[n][1], acc, 0, 0, 0);
      acc = __builtin_amdgcn_mfma_f32_16x16x32_bf16(al0, b1h[n][0], acc, 0, 0, 0);
      acc = __builtin_amdgcn_mfma_f32_16x16x32_bf16(al1, b1h[n][1], acc, 0, 0, 0);
      const int j = n * 16 + lrow;
      #pragma unroll
      for (int i = 0; i < 4; ++i) {
        const int rl = mt * 16 + lpart * 4 + i;
        int r = base_r + rl; if (r >= R_RES) r -= R_RES;
        const float z = acc[i] + bgv[n];
        const float g = 1.0f / (1.0f + __expf(-z));
        const float t = g * od[(size_t)r * HC + j];
        const int off = ((rl * 256 + j * 4)) ^ ((rl & 7) << 4);
        *reinterpret_cast<float*>(reinterpret_cast<char*>(tw) + off) = t;
      }
    }
  }

  __syncthreads();  // safe ordering of LDS writes -> reads (also within wave)

  // ---- B2 frags (woT hi/lo) replace B1 ----
  bf16x8 b2h[4][2], b2l[4][2];
  #pragma unroll
  for (int n = 0; n < 4; ++n) {
    #pragma unroll
    for (int k = 0; k < 2; ++k) {
      const int idx = (n * 16 + lrow) * 64 + k * 32 + lpart * 8;
      b2h[n][k] = *reinterpret_cast<const bf16x8*>(woT_hi + idx);
      b2l[n][k] = *reinterpret_cast<const bf16x8*>(woT_lo + idx);
    }
  }

  // ---- Pass 2: t -> GEMM2 -> out ----
  #pragma unroll
  for (int mt = 0; mt < 4; ++mt) {
    const int rl2 = mt * 16 + lrow;
    const int swz = (rl2 & 7) << 4;
    bf16x8 ah0, al0, ah1, al1;
    {
      const int a0 = rl2 * 256 + lpart * 32;         // k-chunk 0: j = lpart*8..
      const int a1 = rl2 * 256 + 128 + lpart * 32;   // k-chunk 1: j = 32+lpart*8..
      char* tb = reinterpret_cast<char*>(tw);
      float4 u0 = *reinterpret_cast<float4*>(tb + (a0 ^ swz));
      float4 u1 = *reinterpret_cast<float4*>(tb + ((a0 + 16) ^ swz));
      float4 u2 = *reinterpret_cast<float4*>(tb + (a1 ^ swz));
      float4 u3 = *reinterpret_cast<float4*>(tb + ((a1 + 16) ^ swz));
      float t0[8] = {u0.x, u0.y, u0.z, u0.w, u1.x, u1.y, u1.z, u1.w};
      float t1[8] = {u2.x, u2.y, u2.z, u2.w, u3.x, u3.y, u3.z, u3.w};
      #pragma unroll
      for (int e = 0; e < 8; ++e) {
        short h = f2bf(t0[e]);
        ah0[e] = h; al0[e] = f2bf(t0[e] - bf2f(h));
        h = f2bf(t1[e]);
        ah1[e] = h; al1[e] = f2bf(t1[e] - bf2f(h));
      }
    }
    #pragma unroll
    for (int n = 0; n < 4; ++n) {
      f32x4 acc = {0.f, 0.f, 0.f, 0.f};
      acc = __builtin_amdgcn_mfma_f32_16x16x32_bf16(ah0, b2h[n][0], acc, 0, 0, 0);
      acc = __builtin_amdgcn_mfma_f32_16x16x32_bf16(ah1, b2h[n][1], acc, 0, 0, 0);
      acc = __builtin_amdgcn_mfma_f32_16x16x32_bf16(ah0, b2l[n][0], acc, 0, 0, 0);
      acc = __builtin_amdgcn_mfma_f32_16x16x32_bf16(ah1, b2l[n][1], acc, 0, 0, 0);
      acc = __builtin_amdgcn_mfma_f32_16x16x32_bf16(al0, b2h[n][0], acc, 0, 0, 0);
      acc = __builtin_amdgcn_mfma_f32_16x16x32_bf16(al1, b2h[n][1], acc, 0, 0, 0);
      const int cc = n * 16 + lrow;
      #pragma unroll
      for (int i = 0; i < 4; ++i) {
        const size_t grow = base + mt * 16 + lpart * 4 + i;
        out[grow * CIN + cc] = acc[i] + bov[n];
      }
    }
  }
}

// ---------------------------------------------------------------------------
extern "C" void kernel_launch(void* const* d_in, const int* in_sizes, int n_in,
                              void* d_out, int out_size, void* d_ws, size_t ws_size,
                              hipStream_t stream) {
  const float* m    = (const float*)d_in[0];
  const float* mask = (const float*)d_in[1];
  const float* ln_w = (const float*)d_in[2];
  const float* ln_b = (const float*)d_in[3];
  const float* wq   = (const float*)d_in[4];
  const float* wk   = (const float*)d_in[5];
  const float* wv   = (const float*)d_in[6];
  const float* wg   = (const float*)d_in[7];
  const float* bg   = (const float*)d_in[8];
  const float* wo   = (const float*)d_in[9];
  const float* bo   = (const float*)d_in[10];
  float* out = (float*)d_out;

  const size_t sizeK   = (size_t)R_RES * S_SEQ * CHD * sizeof(float);   // 25.2 MB
  const size_t sizeQP  = (size_t)4 * R_RES * CIN * sizeof(float);       // 393 KB
  const size_t sizeQM  = (size_t)4 * R_RES * sizeof(float);
  const size_t sizeO   = (size_t)R_RES * HC * sizeof(float);
  const size_t sizeW   = (size_t)HC * CIN * sizeof(short);              // 8 KB
  const size_t sizeWKV = (size_t)16 * CIN * sizeof(short);              // 2 KB

  char* ws = (char*)d_ws;
  float* Kd         = (float*)(ws);
  float* Vd         = (float*)(ws + sizeK);
  float* qpool_part = (float*)(ws + 2 * sizeK);
  float* qm_part    = (float*)(ws + 2 * sizeK + sizeQP);
  float* od         = (float*)(ws + 2 * sizeK + sizeQP + sizeQM);
  char* wbase       = ws + 2 * sizeK + sizeQP + sizeQM + sizeO;
  short* wgT_hi  = (short*)(wbase);
  short* wgT_lo  = (short*)(wbase + sizeW);
  short* woT_hi  = (short*)(wbase + 2 * sizeW);
  short* woT_lo  = (short*)(wbase + 3 * sizeW);
  short* wkvT_hi = (short*)(wbase + 4 * sizeW);
  short* wkvT_lo = (short*)(wbase + 4 * sizeW + sizeWKV);
  float* bkv     = (float*)(wbase + 4 * sizeW + 2 * sizeWKV);

  k0_prep<<<(HC * CIN + 255) / 256, 256, 0, stream>>>(
      wg, wo, wk, wv, ln_w, ln_b,
      wgT_hi, wgT_lo, woT_hi, woT_lo, wkvT_hi, wkvT_lo, bkv);

  k1_mfma<<<dim3(R_RES, 4), 256, 0, stream>>>(
      m, mask, wkvT_hi, wkvT_lo, bkv, Kd, Vd, qpool_part, qm_part);

  k2_attn<<<R_RES, 256, 0, stream>>>(
      mask, ln_w, ln_b, wq, qpool_part, qm_part, Kd, Vd, od);

  k3_mfma<<<(S_SEQ * R_RES) / 128, 128, 0, stream>>>(
      m, ln_w, ln_b, wgT_hi, wgT_lo, woT_hi, woT_lo, bg, bo, od, out);
}

// Round 19
// 214.423 us; speedup vs baseline: 1.1068x; 1.0108x over previous
//
#include <hip/hip_runtime.h>
#include <hip/hip_bf16.h>

#define S_SEQ 2048
#define R_RES 384
#define CIN   64
#define HC    64
#define NH    8
#define CHD   8

using bf16x8 = __attribute__((ext_vector_type(8))) short;
using f32x4  = __attribute__((ext_vector_type(4))) float;

__device__ __forceinline__ short f2bf(float v) {
  __hip_bfloat16 h = __float2bfloat16(v);
  union { __hip_bfloat16 b; short s; } u; u.b = h; return u.s;
}
__device__ __forceinline__ float bf2f(short s) {
  union { short s; __hip_bfloat16 b; } u; u.s = s; return __bfloat162float(u.b);
}

// ---------------------------------------------------------------------------
// Kernel 0: prep weight tables. (R15 verbatim)
// ---------------------------------------------------------------------------
__global__ __launch_bounds__(256) void k0_prep(
    const float* __restrict__ wg, const float* __restrict__ wo,
    const float* __restrict__ wk, const float* __restrict__ wv,
    const float* __restrict__ ln_w, const float* __restrict__ ln_b,
    short* __restrict__ wgT_hi, short* __restrict__ wgT_lo,
    short* __restrict__ woT_hi, short* __restrict__ woT_lo,
    short* __restrict__ wkvT_hi, short* __restrict__ wkvT_lo,
    float* __restrict__ bkv) {
  const int idx = blockIdx.x * 256 + threadIdx.x;
  if (idx < 16) {
    float s = 0.f;
    for (int c = 0; c < CIN; ++c)
      s += ln_b[c] * ((idx < 8) ? wk[c * CHD + idx] : wv[c * CHD + (idx - 8)]);
    bkv[idx] = s;
  }
  if (idx < 16 * CIN) {  // wkvT (folded)
    const int a = idx >> 6, c = idx & 63;
    const float w = ln_w[c] * ((a < 8) ? wk[c * CHD + a] : wv[c * CHD + (a - 8)]);
    short h = f2bf(w);
    wkvT_hi[idx] = h; wkvT_lo[idx] = f2bf(w - bf2f(h));
  }
  if (idx >= HC * CIN) return;
  const int a = idx >> 6;   // out row
  const int b = idx & 63;   // out col
  const float g = wg[b * HC + a];
  short gh = f2bf(g);
  wgT_hi[idx] = gh; wgT_lo[idx] = f2bf(g - bf2f(gh));
  const float o = wo[b * CIN + a];
  short oh = f2bf(o);
  woT_hi[idx] = oh; woT_lo[idx] = f2bf(o - bf2f(oh));
}

// ---------------------------------------------------------------------------
// Kernel MT: transpose mask [S][R] -> maskT [R][S] (LDS-tiled, coalesced
// both sides). grid (S/32, R/32) x 256. ~3 MB moved, ~2 us.
// ---------------------------------------------------------------------------
__global__ __launch_bounds__(256) void k_mt(
    const float* __restrict__ mask, float* __restrict__ maskT) {
  __shared__ float tile[32][33];
  const int s0 = blockIdx.x * 32, r0 = blockIdx.y * 32;
  const int tx = threadIdx.x & 31, ty = threadIdx.x >> 5;  // 32x8
  #pragma unroll
  for (int i = ty; i < 32; i += 8)
    tile[i][tx] = mask[(size_t)(s0 + i) * R_RES + r0 + tx];
  __syncthreads();
  #pragma unroll
  for (int i = ty; i < 32; i += 8)
    maskT[(size_t)(r0 + i) * S_SEQ + s0 + tx] = tile[tx][i];
}

// ---------------------------------------------------------------------------
// Kernel 1 (MFMA): LN + K/V projection + masked pooled sums.
// R15 body; ONLY change: mask read via maskT (coalesced: 16 lrow-lanes read
// 16 consecutive floats).
// ---------------------------------------------------------------------------
__global__ __launch_bounds__(256) void k1_mfma(
    const float* __restrict__ m, const float* __restrict__ maskT,
    const short* __restrict__ wkvT_hi, const short* __restrict__ wkvT_lo,
    const float* __restrict__ bkv,
    float* __restrict__ Kd, float* __restrict__ Vd,
    float* __restrict__ qpool_part, float* __restrict__ qm_part) {
  const int r = blockIdx.x;
  const int chunk = blockIdx.y;  // 0..3
  const int tid = threadIdx.x;
  const int wave = tid >> 6;
  const int lane = tid & 63;
  const int lrow = lane & 15;
  const int lpart = lane >> 4;
  const int s_base = chunk * 512 + wave * 128;

  __shared__ float redA[4][CIN];
  __shared__ float redM[4];

  bf16x8 kvh[2], kvl[2];
  #pragma unroll
  for (int k = 0; k < 2; ++k) {
    const int idx = lrow * 64 + k * 32 + lpart * 8;
    kvh[k] = *reinterpret_cast<const bf16x8*>(wkvT_hi + idx);
    kvl[k] = *reinterpret_cast<const bf16x8*>(wkvT_lo + idx);
  }
  const float4 bkvq = *reinterpret_cast<const float4*>(bkv + lpart * 4);

  float qacc[16];
  #pragma unroll
  for (int e = 0; e < 16; ++e) qacc[e] = 0.f;
  float macc = 0.f;

  for (int t = 0; t < 8; ++t) {
    const int srow = s_base + t * 16 + lrow;
    const float* mrow = m + ((size_t)srow * R_RES + r) * CIN;
    float x0[8], x1[8];
    {
      const float4* p0 = reinterpret_cast<const float4*>(mrow + lpart * 8);
      const float4* p1 = reinterpret_cast<const float4*>(mrow + 32 + lpart * 8);
      float4 a = p0[0], b = p0[1], c = p1[0], d = p1[1];
      x0[0]=a.x; x0[1]=a.y; x0[2]=a.z; x0[3]=a.w; x0[4]=b.x; x0[5]=b.y; x0[6]=b.z; x0[7]=b.w;
      x1[0]=c.x; x1[1]=c.y; x1[2]=c.z; x1[3]=c.w; x1[4]=d.x; x1[5]=d.y; x1[6]=d.z; x1[7]=d.w;
    }
    const float mk = maskT[(size_t)r * S_SEQ + srow];

    float s = 0.f;
    #pragma unroll
    for (int e = 0; e < 8; ++e) s += x0[e] + x1[e];
    s += __shfl_xor(s, 16, 64);
    s += __shfl_xor(s, 32, 64);
    const float mean = s * (1.0f / CIN);
    float vs = 0.f;
    #pragma unroll
    for (int e = 0; e < 8; ++e) {
      float d0 = x0[e] - mean, d1 = x1[e] - mean;
      vs += d0 * d0 + d1 * d1;
    }
    vs += __shfl_xor(vs, 16, 64);
    vs += __shfl_xor(vs, 32, 64);
    const float rstd = rsqrtf(vs * (1.0f / CIN) + 1e-5f);

    bf16x8 ah0, al0, ah1, al1;
    #pragma unroll
    for (int e = 0; e < 8; ++e) {
      const float xh0 = (x0[e] - mean) * rstd;
      const float xh1 = (x1[e] - mean) * rstd;
      qacc[e]     += mk * xh0;
      qacc[8 + e] += mk * xh1;
      short h = f2bf(xh0);
      ah0[e] = h; al0[e] = f2bf(xh0 - bf2f(h));
      h = f2bf(xh1);
      ah1[e] = h; al1[e] = f2bf(xh1 - bf2f(h));
    }
    macc += mk;

    f32x4 a = {0.f, 0.f, 0.f, 0.f};
    a = __builtin_amdgcn_mfma_f32_16x16x32_bf16(kvh[0], ah0, a, 0, 0, 0);
    a = __builtin_amdgcn_mfma_f32_16x16x32_bf16(kvh[1], ah1, a, 0, 0, 0);
    a = __builtin_amdgcn_mfma_f32_16x16x32_bf16(kvl[0], ah0, a, 0, 0, 0);
    a = __builtin_amdgcn_mfma_f32_16x16x32_bf16(kvl[1], ah1, a, 0, 0, 0);
    a = __builtin_amdgcn_mfma_f32_16x16x32_bf16(kvh[0], al0, a, 0, 0, 0);
    a = __builtin_amdgcn_mfma_f32_16x16x32_bf16(kvh[1], al1, a, 0, 0, 0);

    const size_t off = ((size_t)r * S_SEQ + srow) * CHD + (lpart & 1) * 4;
    float* dst = ((lpart & 2) ? Vd : Kd) + off;
    *reinterpret_cast<float4*>(dst) =
        make_float4(a[0] + bkvq.x, a[1] + bkvq.y, a[2] + bkvq.z, a[3] + bkvq.w);
  }

  #pragma unroll
  for (int off = 1; off <= 8; off <<= 1) {
    #pragma unroll
    for (int e = 0; e < 16; ++e) qacc[e] += __shfl_xor(qacc[e], off, 64);
    macc += __shfl_xor(macc, off, 64);
  }
  if (lrow == 0) {
    #pragma unroll
    for (int e = 0; e < 8; ++e) {
      redA[wave][lpart * 8 + e] = qacc[e];
      redA[wave][32 + lpart * 8 + e] = qacc[8 + e];
    }
    if (lpart == 0) redM[wave] = macc;
  }
  __syncthreads();
  if (tid < CIN) {
    const float tot = redA[0][tid] + redA[1][tid] + redA[2][tid] + redA[3][tid];
    qpool_part[((size_t)chunk * R_RES + r) * CIN + tid] = tot;
  }
  if (tid == 0)
    qm_part[chunk * R_RES + r] = redM[0] + redM[1] + redM[2] + redM[3];
}

// ---------------------------------------------------------------------------
// Kernel 2: per-residue global attention — single-pass online softmax.
// R13/R15 body; ONLY change: mask read via maskT (lanes read contiguous
// floats -> coalesced 1KB wave segments).
// ---------------------------------------------------------------------------
__global__ __launch_bounds__(256) void k2_attn(
    const float* __restrict__ maskT,
    const float* __restrict__ ln_w, const float* __restrict__ ln_b,
    const float* __restrict__ wq,
    const float* __restrict__ qpool_part, const float* __restrict__ qm_part,
    const float* __restrict__ Kd, const float* __restrict__ Vd,
    float* __restrict__ od) {
  const int r = blockIdx.x;
  const int tid = threadIdx.x;
  const int lane = tid & 63;
  const int wave = tid >> 6;

  __shared__ float s_q[HC];
  __shared__ float s_qp[CIN];
  __shared__ float redw[4][CIN];
  __shared__ float dred[4][NH];
  __shared__ float mred[4][NH];

  const float msum_tot = qm_part[0 * R_RES + r] + qm_part[1 * R_RES + r] +
                         qm_part[2 * R_RES + r] + qm_part[3 * R_RES + r];

  if (tid < CIN) {
    float A = 0.f;
    #pragma unroll
    for (int ch = 0; ch < 4; ++ch)
      A += qpool_part[((size_t)ch * R_RES + r) * CIN + tid];
    s_qp[tid] = (ln_w[tid] * A + ln_b[tid] * msum_tot) / (msum_tot + 1e-10f);
  }
  __syncthreads();
  if (tid < HC) {
    float qj = 0.f;
    for (int c = 0; c < CIN; ++c) qj += s_qp[c] * wq[c * HC + tid];
    s_q[tid] = qj * 0.35355339059327373f;  // 1/sqrt(8)
  }
  __syncthreads();

  // ---- single online pass over S ----
  float mh[NH], dp[NH];
  #pragma unroll
  for (int h = 0; h < NH; ++h) { mh[h] = -1e30f; dp[h] = 0.f; }
  float opart[HC];
  #pragma unroll
  for (int i = 0; i < HC; ++i) opart[i] = 0.f;

  for (int s = tid; s < S_SEQ; s += 256) {
    float kk[CHD], vv[CHD];
    const float4* kp = reinterpret_cast<const float4*>(Kd + ((size_t)r * S_SEQ + s) * CHD);
    const float4* vp = reinterpret_cast<const float4*>(Vd + ((size_t)r * S_SEQ + s) * CHD);
    float4 a = kp[0], b = kp[1], c4 = vp[0], d4 = vp[1];
    kk[0] = a.x; kk[1] = a.y; kk[2] = a.z; kk[3] = a.w;
    kk[4] = b.x; kk[5] = b.y; kk[6] = b.z; kk[7] = b.w;
    vv[0] = c4.x; vv[1] = c4.y; vv[2] = c4.z; vv[3] = c4.w;
    vv[4] = d4.x; vv[5] = d4.y; vv[6] = d4.z; vv[7] = d4.w;
    const float madd = 1e9f * (maskT[(size_t)r * S_SEQ + s] - 1.0f);
    #pragma unroll
    for (int h = 0; h < NH; ++h) {
      float l = madd;
      #pragma unroll
      for (int j = 0; j < CHD; ++j) l += s_q[h * CHD + j] * kk[j];
      const float newm = fmaxf(mh[h], l);
      const float sc = __expf(mh[h] - newm);  // 1 if max unchanged
      const float p  = __expf(l - newm);
      dp[h] = dp[h] * sc + p;
      #pragma unroll
      for (int j = 0; j < CHD; ++j)
        opart[h * CHD + j] = opart[h * CHD + j] * sc + p * vv[j];
      mh[h] = newm;
    }
  }

  // ---- cross-lane/wave max ----
  float wm[NH];
  #pragma unroll
  for (int h = 0; h < NH; ++h) {
    wm[h] = mh[h];
    #pragma unroll
    for (int off = 32; off >= 1; off >>= 1)
      wm[h] = fmaxf(wm[h], __shfl_xor(wm[h], off, 64));
  }
  if (lane == 0) {
    #pragma unroll
    for (int h = 0; h < NH; ++h) mred[wave][h] = wm[h];
  }
  __syncthreads();
  #pragma unroll
  for (int h = 0; h < NH; ++h)
    wm[h] = fmaxf(fmaxf(mred[0][h], mred[1][h]), fmaxf(mred[2][h], mred[3][h]));

  // ---- rescale lane-local partials to global max (exact) ----
  #pragma unroll
  for (int h = 0; h < NH; ++h) {
    const float sc = __expf(mh[h] - wm[h]);
    dp[h] *= sc;
    #pragma unroll
    for (int j = 0; j < CHD; ++j) opart[h * CHD + j] *= sc;
  }

  // ---- reductions ----
  #pragma unroll
  for (int h = 0; h < NH; ++h) {
    float v = dp[h];
    #pragma unroll
    for (int off = 32; off >= 1; off >>= 1) v += __shfl_xor(v, off, 64);
    dp[h] = v;
  }
  if (lane == 0) {
    #pragma unroll
    for (int h = 0; h < NH; ++h) dred[wave][h] = dp[h];
  }
  float keep = 0.f;
  #pragma unroll
  for (int c = 0; c < HC; ++c) {
    float val = opart[c];
    #pragma unroll
    for (int off = 32; off >= 1; off >>= 1) val += __shfl_xor(val, off, 64);
    if (lane == c) keep = val;
  }
  redw[wave][lane] = keep;
  __syncthreads();
  if (tid < HC) {
    const float tot = redw[0][tid] + redw[1][tid] + redw[2][tid] + redw[3][tid];
    const int h = tid >> 3;
    const float den = dred[0][h] + dred[1][h] + dred[2][h] + dred[3][h];
    od[(size_t)r * HC + tid] = tot / den;
  }
}

// ---------------------------------------------------------------------------
// Kernel 3 (MFMA): EXACT round-9 kernel (measured 135 us). Do not edit.
// ---------------------------------------------------------------------------
__global__ __launch_bounds__(128) void k3_mfma(
    const float* __restrict__ m,
    const float* __restrict__ ln_w, const float* __restrict__ ln_b,
    const short* __restrict__ wgT_hi, const short* __restrict__ wgT_lo,
    const short* __restrict__ woT_hi, const short* __restrict__ woT_lo,
    const float* __restrict__ bg, const float* __restrict__ bo,
    const float* __restrict__ od, float* __restrict__ out) {
  const int tid = threadIdx.x;
  const int wave = tid >> 6;
  const int lane = tid & 63;
  const int lrow = lane & 15;   // A/B frag row index
  const int lpart = lane >> 4;  // 0..3, k-chunk owner
  const size_t base = (size_t)blockIdx.x * 128 + (size_t)wave * 64;
  const int base_r = (int)(base % R_RES);

  __shared__ float t_lds[2][64 * 64];  // per-wave t tile, XOR-swizzled rows
  float* tw = t_lds[wave];

  // per-lane bias values for columns j = n*16 + lrow
  float bgv[4], bov[4];
  #pragma unroll
  for (int n = 0; n < 4; ++n) { bgv[n] = bg[n * 16 + lrow]; bov[n] = bo[n * 16 + lrow]; }

  // LN params for this lane's two k-chunks: c = lpart*8+e and 32+lpart*8+e
  float lw0[8], lb0[8], lw1[8], lb1[8];
  {
    const float4* w0 = reinterpret_cast<const float4*>(ln_w + lpart * 8);
    const float4* w1 = reinterpret_cast<const float4*>(ln_w + 32 + lpart * 8);
    const float4* b0 = reinterpret_cast<const float4*>(ln_b + lpart * 8);
    const float4* b1 = reinterpret_cast<const float4*>(ln_b + 32 + lpart * 8);
    float4 a = w0[0], b = w0[1], c = w1[0], d = w1[1];
    lw0[0]=a.x; lw0[1]=a.y; lw0[2]=a.z; lw0[3]=a.w; lw0[4]=b.x; lw0[5]=b.y; lw0[6]=b.z; lw0[7]=b.w;
    lw1[0]=c.x; lw1[1]=c.y; lw1[2]=c.z; lw1[3]=c.w; lw1[4]=d.x; lw1[5]=d.y; lw1[6]=d.z; lw1[7]=d.w;
    a = b0[0]; b = b0[1]; c = b1[0]; d = b1[1];
    lb0[0]=a.x; lb0[1]=a.y; lb0[2]=a.z; lb0[3]=a.w; lb0[4]=b.x; lb0[5]=b.y; lb0[6]=b.z; lb0[7]=b.w;
    lb1[0]=c.x; lb1[1]=c.y; lb1[2]=c.z; lb1[3]=c.w; lb1[4]=d.x; lb1[5]=d.y; lb1[6]=d.z; lb1[7]=d.w;
  }

  // ---- B1 frags (wgT hi/lo): [n][k], lane reads wgT[n*16+lrow][k*32 + lpart*8 ..+7]
  bf16x8 b1h[4][2], b1l[4][2];
  #pragma unroll
  for (int n = 0; n < 4; ++n) {
    #pragma unroll
    for (int k = 0; k < 2; ++k) {
      const int idx = (n * 16 + lrow) * 64 + k * 32 + lpart * 8;
      b1h[n][k] = *reinterpret_cast<const bf16x8*>(wgT_hi + idx);
      b1l[n][k] = *reinterpret_cast<const bf16x8*>(wgT_lo + idx);
    }
  }

  // ---- Pass 1: LN -> GEMM1 -> sigmoid*o -> t to LDS ----
  #pragma unroll
  for (int mt = 0; mt < 4; ++mt) {
    const size_t grow = base + mt * 16 + lrow;
    const float* mrow = m + grow * CIN;
    float x0[8], x1[8];
    {
      const float4* p0 = reinterpret_cast<const float4*>(mrow + lpart * 8);
      const float4* p1 = reinterpret_cast<const float4*>(mrow + 32 + lpart * 8);
      float4 a = p0[0], b = p0[1], c = p1[0], d = p1[1];
      x0[0]=a.x; x0[1]=a.y; x0[2]=a.z; x0[3]=a.w; x0[4]=b.x; x0[5]=b.y; x0[6]=b.z; x0[7]=b.w;
      x1[0]=c.x; x1[1]=c.y; x1[2]=c.z; x1[3]=c.w; x1[4]=d.x; x1[5]=d.y; x1[6]=d.z; x1[7]=d.w;
    }
    float s = 0.f;
    #pragma unroll
    for (int e = 0; e < 8; ++e) s += x0[e] + x1[e];
    s += __shfl_xor(s, 16, 64);
    s += __shfl_xor(s, 32, 64);
    const float mean = s * (1.0f / CIN);
    float vs = 0.f;
    #pragma unroll
    for (int e = 0; e < 8; ++e) {
      float d0 = x0[e] - mean, d1 = x1[e] - mean;
      vs += d0 * d0 + d1 * d1;
    }
    vs += __shfl_xor(vs, 16, 64);
    vs += __shfl_xor(vs, 32, 64);
    const float rstd = rsqrtf(vs * (1.0f / CIN) + 1e-5f);

    bf16x8 ah0, al0, ah1, al1;
    #pragma unroll
    for (int e = 0; e < 8; ++e) {
      float xn = (x0[e] - mean) * rstd * lw0[e] + lb0[e];
      short h = f2bf(xn);
      ah0[e] = h; al0[e] = f2bf(xn - bf2f(h));
      xn = (x1[e] - mean) * rstd * lw1[e] + lb1[e];
      h = f2bf(xn);
      ah1[e] = h; al1[e] = f2bf(xn - bf2f(h));
    }

    #pragma unroll
    for (int n = 0; n < 4; ++n) {
      f32x4 acc = {0.f, 0.f, 0.f, 0.f};
      acc = __builtin_amdgcn_mfma_f32_16x16x32_bf16(ah0, b1h[n][0], acc, 0, 0, 0);
      acc = __builtin_amdgcn_mfma_f32_16x16x32_bf16(ah1, b1h[n][1], acc, 0, 0, 0);
      acc = __builtin_amdgcn_mfma_f32_16x16x32_bf16(ah0, b1l[n][0], acc, 0, 0, 0);
      acc = __builtin_amdgcn_mfma_f32_16x16x32_bf16(ah1, b1l[n][1], acc, 0, 0, 0);
      acc = __builtin_amdgcn_mfma_f32_16x16x32_bf16(al0, b1h[n][0], acc, 0, 0, 0);
      acc = __builtin_amdgcn_mfma_f32_16x16x32_bf16(al1, b1h[n][1], acc, 0, 0, 0);
      const int j = n * 16 + lrow;
      #pragma unroll
      for (int i = 0; i < 4; ++i) {
        const int rl = mt * 16 + lpart * 4 + i;
        int r = base_r + rl; if (r >= R_RES) r -= R_RES;
        const float z = acc[i] + bgv[n];
        const float g = 1.0f / (1.0f + __expf(-z));
        const float t = g * od[(size_t)r * HC + j];
        const int off = ((rl * 256 + j * 4)) ^ ((rl & 7) << 4);
        *reinterpret_cast<float*>(reinterpret_cast<char*>(tw) + off) = t;
      }
    }
  }

  __syncthreads();  // safe ordering of LDS writes -> reads (also within wave)

  // ---- B2 frags (woT hi/lo) replace B1 ----
  bf16x8 b2h[4][2], b2l[4][2];
  #pragma unroll
  for (int n = 0; n < 4; ++n) {
    #pragma unroll
    for (int k = 0; k < 2; ++k) {
      const int idx = (n * 16 + lrow) * 64 + k * 32 + lpart * 8;
      b2h[n][k] = *reinterpret_cast<const bf16x8*>(woT_hi + idx);
      b2l[n][k] = *reinterpret_cast<const bf16x8*>(woT_lo + idx);
    }
  }

  // ---- Pass 2: t -> GEMM2 -> out ----
  #pragma unroll
  for (int mt = 0; mt < 4; ++mt) {
    const int rl2 = mt * 16 + lrow;
    const int swz = (rl2 & 7) << 4;
    bf16x8 ah0, al0, ah1, al1;
    {
      const int a0 = rl2 * 256 + lpart * 32;         // k-chunk 0: j = lpart*8..
      const int a1 = rl2 * 256 + 128 + lpart * 32;   // k-chunk 1: j = 32+lpart*8..
      char* tb = reinterpret_cast<char*>(tw);
      float4 u0 = *reinterpret_cast<float4*>(tb + (a0 ^ swz));
      float4 u1 = *reinterpret_cast<float4*>(tb + ((a0 + 16) ^ swz));
      float4 u2 = *reinterpret_cast<float4*>(tb + (a1 ^ swz));
      float4 u3 = *reinterpret_cast<float4*>(tb + ((a1 + 16) ^ swz));
      float t0[8] = {u0.x, u0.y, u0.z, u0.w, u1.x, u1.y, u1.z, u1.w};
      float t1[8] = {u2.x, u2.y, u2.z, u2.w, u3.x, u3.y, u3.z, u3.w};
      #pragma unroll
      for (int e = 0; e < 8; ++e) {
        short h = f2bf(t0[e]);
        ah0[e] = h; al0[e] = f2bf(t0[e] - bf2f(h));
        h = f2bf(t1[e]);
        ah1[e] = h; al1[e] = f2bf(t1[e] - bf2f(h));
      }
    }
    #pragma unroll
    for (int n = 0; n < 4; ++n) {
      f32x4 acc = {0.f, 0.f, 0.f, 0.f};
      acc = __builtin_amdgcn_mfma_f32_16x16x32_bf16(ah0, b2h[n][0], acc, 0, 0, 0);
      acc = __builtin_amdgcn_mfma_f32_16x16x32_bf16(ah1, b2h[n][1], acc, 0, 0, 0);
      acc = __builtin_amdgcn_mfma_f32_16x16x32_bf16(ah0, b2l[n][0], acc, 0, 0, 0);
      acc = __builtin_amdgcn_mfma_f32_16x16x32_bf16(ah1, b2l[n][1], acc, 0, 0, 0);
      acc = __builtin_amdgcn_mfma_f32_16x16x32_bf16(al0, b2h[n][0], acc, 0, 0, 0);
      acc = __builtin_amdgcn_mfma_f32_16x16x32_bf16(al1, b2h[n][1], acc, 0, 0, 0);
      const int cc = n * 16 + lrow;
      #pragma unroll
      for (int i = 0; i < 4; ++i) {
        const size_t grow = base + mt * 16 + lpart * 4 + i;
        out[grow * CIN + cc] = acc[i] + bov[n];
      }
    }
  }
}

// ---------------------------------------------------------------------------
extern "C" void kernel_launch(void* const* d_in, const int* in_sizes, int n_in,
                              void* d_out, int out_size, void* d_ws, size_t ws_size,
                              hipStream_t stream) {
  const float* m    = (const float*)d_in[0];
  const float* mask = (const float*)d_in[1];
  const float* ln_w = (const float*)d_in[2];
  const float* ln_b = (const float*)d_in[3];
  const float* wq   = (const float*)d_in[4];
  const float* wk   = (const float*)d_in[5];
  const float* wv   = (const float*)d_in[6];
  const float* wg   = (const float*)d_in[7];
  const float* bg   = (const float*)d_in[8];
  const float* wo   = (const float*)d_in[9];
  const float* bo   = (const float*)d_in[10];
  float* out = (float*)d_out;

  const size_t sizeK   = (size_t)R_RES * S_SEQ * CHD * sizeof(float);   // 25.2 MB
  const size_t sizeQP  = (size_t)4 * R_RES * CIN * sizeof(float);       // 393 KB
  const size_t sizeQM  = (size_t)4 * R_RES * sizeof(float);
  const size_t sizeO   = (size_t)R_RES * HC * sizeof(float);
  const size_t sizeW   = (size_t)HC * CIN * sizeof(short);              // 8 KB
  const size_t sizeWKV = (size_t)16 * CIN * sizeof(short);              // 2 KB
  const size_t sizeMT  = (size_t)S_SEQ * R_RES * sizeof(float);         // 3.1 MB

  char* ws = (char*)d_ws;
  float* Kd         = (float*)(ws);
  float* Vd         = (float*)(ws + sizeK);
  float* qpool_part = (float*)(ws + 2 * sizeK);
  float* qm_part    = (float*)(ws + 2 * sizeK + sizeQP);
  float* od         = (float*)(ws + 2 * sizeK + sizeQP + sizeQM);
  char* wbase       = ws + 2 * sizeK + sizeQP + sizeQM + sizeO;
  short* wgT_hi  = (short*)(wbase);
  short* wgT_lo  = (short*)(wbase + sizeW);
  short* woT_hi  = (short*)(wbase + 2 * sizeW);
  short* woT_lo  = (short*)(wbase + 3 * sizeW);
  short* wkvT_hi = (short*)(wbase + 4 * sizeW);
  short* wkvT_lo = (short*)(wbase + 4 * sizeW + sizeWKV);
  float* bkv     = (float*)(wbase + 4 * sizeW + 2 * sizeWKV);
  float* maskT   = (float*)(wbase + 4 * sizeW + 2 * sizeWKV + 256);

  k0_prep<<<(HC * CIN + 255) / 256, 256, 0, stream>>>(
      wg, wo, wk, wv, ln_w, ln_b,
      wgT_hi, wgT_lo, woT_hi, woT_lo, wkvT_hi, wkvT_lo, bkv);

  k_mt<<<dim3(S_SEQ / 32, R_RES / 32), 256, 0, stream>>>(mask, maskT);

  k1_mfma<<<dim3(R_RES, 4), 256, 0, stream>>>(
      m, maskT, wkvT_hi, wkvT_lo, bkv, Kd, Vd, qpool_part, qm_part);

  k2_attn<<<R_RES, 256, 0, stream>>>(
      maskT, ln_w, ln_b, wq, qpool_part, qm_part, Kd, Vd, od);

  k3_mfma<<<(S_SEQ * R_RES) / 128, 128, 0, stream>>>(
      m, ln_w, ln_b, wgT_hi, wgT_lo, woT_hi, woT_lo, bg, bo, od, out);
}

// Round 20
// 213.746 us; speedup vs baseline: 1.1103x; 1.0032x over previous
//
#include <hip/hip_runtime.h>
#include <hip/hip_bf16.h>

#define S_SEQ 2048
#define R_RES 384
#define CIN   64
#define HC    64
#define NH    8
#define CHD   8

using bf16x8 = __attribute__((ext_vector_type(8))) short;
using f32x4  = __attribute__((ext_vector_type(4))) float;

__device__ __forceinline__ short f2bf(float v) {
  __hip_bfloat16 h = __float2bfloat16(v);
  union { __hip_bfloat16 b; short s; } u; u.b = h; return u.s;
}
__device__ __forceinline__ float bf2f(short s) {
  union { short s; __hip_bfloat16 b; } u; u.s = s; return __bfloat162float(u.b);
}

// ---------------------------------------------------------------------------
// Kernel 0: prep weight tables. (R15 verbatim)
// ---------------------------------------------------------------------------
__global__ __launch_bounds__(256) void k0_prep(
    const float* __restrict__ wg, const float* __restrict__ wo,
    const float* __restrict__ wk, const float* __restrict__ wv,
    const float* __restrict__ ln_w, const float* __restrict__ ln_b,
    short* __restrict__ wgT_hi, short* __restrict__ wgT_lo,
    short* __restrict__ woT_hi, short* __restrict__ woT_lo,
    short* __restrict__ wkvT_hi, short* __restrict__ wkvT_lo,
    float* __restrict__ bkv) {
  const int idx = blockIdx.x * 256 + threadIdx.x;
  if (idx < 16) {
    float s = 0.f;
    for (int c = 0; c < CIN; ++c)
      s += ln_b[c] * ((idx < 8) ? wk[c * CHD + idx] : wv[c * CHD + (idx - 8)]);
    bkv[idx] = s;
  }
  if (idx < 16 * CIN) {  // wkvT (folded)
    const int a = idx >> 6, c = idx & 63;
    const float w = ln_w[c] * ((a < 8) ? wk[c * CHD + a] : wv[c * CHD + (a - 8)]);
    short h = f2bf(w);
    wkvT_hi[idx] = h; wkvT_lo[idx] = f2bf(w - bf2f(h));
  }
  if (idx >= HC * CIN) return;
  const int a = idx >> 6;   // out row
  const int b = idx & 63;   // out col
  const float g = wg[b * HC + a];
  short gh = f2bf(g);
  wgT_hi[idx] = gh; wgT_lo[idx] = f2bf(g - bf2f(gh));
  const float o = wo[b * CIN + a];
  short oh = f2bf(o);
  woT_hi[idx] = oh; woT_lo[idx] = f2bf(o - bf2f(oh));
}

// ---------------------------------------------------------------------------
// Kernel MT: transpose mask [S][R] -> maskT [R][S] (LDS-tiled, coalesced
// both sides). grid (S/32, R/32) x 256. ~3 MB moved, ~2 us.
// ---------------------------------------------------------------------------
__global__ __launch_bounds__(256) void k_mt(
    const float* __restrict__ mask, float* __restrict__ maskT) {
  __shared__ float tile[32][33];
  const int s0 = blockIdx.x * 32, r0 = blockIdx.y * 32;
  const int tx = threadIdx.x & 31, ty = threadIdx.x >> 5;  // 32x8
  #pragma unroll
  for (int i = ty; i < 32; i += 8)
    tile[i][tx] = mask[(size_t)(s0 + i) * R_RES + r0 + tx];
  __syncthreads();
  #pragma unroll
  for (int i = ty; i < 32; i += 8)
    maskT[(size_t)(r0 + i) * S_SEQ + s0 + tx] = tile[tx][i];
}

// ---------------------------------------------------------------------------
// Kernel 1 (MFMA): LN + K/V projection + masked pooled sums.
// R15 body; mask read via maskT (coalesced).
// ---------------------------------------------------------------------------
__global__ __launch_bounds__(256) void k1_mfma(
    const float* __restrict__ m, const float* __restrict__ maskT,
    const short* __restrict__ wkvT_hi, const short* __restrict__ wkvT_lo,
    const float* __restrict__ bkv,
    float* __restrict__ Kd, float* __restrict__ Vd,
    float* __restrict__ qpool_part, float* __restrict__ qm_part) {
  const int r = blockIdx.x;
  const int chunk = blockIdx.y;  // 0..3
  const int tid = threadIdx.x;
  const int wave = tid >> 6;
  const int lane = tid & 63;
  const int lrow = lane & 15;
  const int lpart = lane >> 4;
  const int s_base = chunk * 512 + wave * 128;

  __shared__ float redA[4][CIN];
  __shared__ float redM[4];

  bf16x8 kvh[2], kvl[2];
  #pragma unroll
  for (int k = 0; k < 2; ++k) {
    const int idx = lrow * 64 + k * 32 + lpart * 8;
    kvh[k] = *reinterpret_cast<const bf16x8*>(wkvT_hi + idx);
    kvl[k] = *reinterpret_cast<const bf16x8*>(wkvT_lo + idx);
  }
  const float4 bkvq = *reinterpret_cast<const float4*>(bkv + lpart * 4);

  float qacc[16];
  #pragma unroll
  for (int e = 0; e < 16; ++e) qacc[e] = 0.f;
  float macc = 0.f;

  for (int t = 0; t < 8; ++t) {
    const int srow = s_base + t * 16 + lrow;
    const float* mrow = m + ((size_t)srow * R_RES + r) * CIN;
    float x0[8], x1[8];
    {
      const float4* p0 = reinterpret_cast<const float4*>(mrow + lpart * 8);
      const float4* p1 = reinterpret_cast<const float4*>(mrow + 32 + lpart * 8);
      float4 a = p0[0], b = p0[1], c = p1[0], d = p1[1];
      x0[0]=a.x; x0[1]=a.y; x0[2]=a.z; x0[3]=a.w; x0[4]=b.x; x0[5]=b.y; x0[6]=b.z; x0[7]=b.w;
      x1[0]=c.x; x1[1]=c.y; x1[2]=c.z; x1[3]=c.w; x1[4]=d.x; x1[5]=d.y; x1[6]=d.z; x1[7]=d.w;
    }
    const float mk = maskT[(size_t)r * S_SEQ + srow];

    float s = 0.f;
    #pragma unroll
    for (int e = 0; e < 8; ++e) s += x0[e] + x1[e];
    s += __shfl_xor(s, 16, 64);
    s += __shfl_xor(s, 32, 64);
    const float mean = s * (1.0f / CIN);
    float vs = 0.f;
    #pragma unroll
    for (int e = 0; e < 8; ++e) {
      float d0 = x0[e] - mean, d1 = x1[e] - mean;
      vs += d0 * d0 + d1 * d1;
    }
    vs += __shfl_xor(vs, 16, 64);
    vs += __shfl_xor(vs, 32, 64);
    const float rstd = rsqrtf(vs * (1.0f / CIN) + 1e-5f);

    bf16x8 ah0, al0, ah1, al1;
    #pragma unroll
    for (int e = 0; e < 8; ++e) {
      const float xh0 = (x0[e] - mean) * rstd;
      const float xh1 = (x1[e] - mean) * rstd;
      qacc[e]     += mk * xh0;
      qacc[8 + e] += mk * xh1;
      short h = f2bf(xh0);
      ah0[e] = h; al0[e] = f2bf(xh0 - bf2f(h));
      h = f2bf(xh1);
      ah1[e] = h; al1[e] = f2bf(xh1 - bf2f(h));
    }
    macc += mk;

    f32x4 a = {0.f, 0.f, 0.f, 0.f};
    a = __builtin_amdgcn_mfma_f32_16x16x32_bf16(kvh[0], ah0, a, 0, 0, 0);
    a = __builtin_amdgcn_mfma_f32_16x16x32_bf16(kvh[1], ah1, a, 0, 0, 0);
    a = __builtin_amdgcn_mfma_f32_16x16x32_bf16(kvl[0], ah0, a, 0, 0, 0);
    a = __builtin_amdgcn_mfma_f32_16x16x32_bf16(kvl[1], ah1, a, 0, 0, 0);
    a = __builtin_amdgcn_mfma_f32_16x16x32_bf16(kvh[0], al0, a, 0, 0, 0);
    a = __builtin_amdgcn_mfma_f32_16x16x32_bf16(kvh[1], al1, a, 0, 0, 0);

    const size_t off = ((size_t)r * S_SEQ + srow) * CHD + (lpart & 1) * 4;
    float* dst = ((lpart & 2) ? Vd : Kd) + off;
    *reinterpret_cast<float4*>(dst) =
        make_float4(a[0] + bkvq.x, a[1] + bkvq.y, a[2] + bkvq.z, a[3] + bkvq.w);
  }

  #pragma unroll
  for (int off = 1; off <= 8; off <<= 1) {
    #pragma unroll
    for (int e = 0; e < 16; ++e) qacc[e] += __shfl_xor(qacc[e], off, 64);
    macc += __shfl_xor(macc, off, 64);
  }
  if (lrow == 0) {
    #pragma unroll
    for (int e = 0; e < 8; ++e) {
      redA[wave][lpart * 8 + e] = qacc[e];
      redA[wave][32 + lpart * 8 + e] = qacc[8 + e];
    }
    if (lpart == 0) redM[wave] = macc;
  }
  __syncthreads();
  if (tid < CIN) {
    const float tot = redA[0][tid] + redA[1][tid] + redA[2][tid] + redA[3][tid];
    qpool_part[((size_t)chunk * R_RES + r) * CIN + tid] = tot;
  }
  if (tid == 0)
    qm_part[chunk * R_RES + r] = redM[0] + redM[1] + redM[2] + redM[3];
}

// ---------------------------------------------------------------------------
// Kernel 2: per-residue global attention — single-pass online softmax.
// R13/R15 body; mask read via maskT (coalesced).
// ---------------------------------------------------------------------------
__global__ __launch_bounds__(256) void k2_attn(
    const float* __restrict__ maskT,
    const float* __restrict__ ln_w, const float* __restrict__ ln_b,
    const float* __restrict__ wq,
    const float* __restrict__ qpool_part, const float* __restrict__ qm_part,
    const float* __restrict__ Kd, const float* __restrict__ Vd,
    float* __restrict__ od) {
  const int r = blockIdx.x;
  const int tid = threadIdx.x;
  const int lane = tid & 63;
  const int wave = tid >> 6;

  __shared__ float s_q[HC];
  __shared__ float s_qp[CIN];
  __shared__ float redw[4][CIN];
  __shared__ float dred[4][NH];
  __shared__ float mred[4][NH];

  const float msum_tot = qm_part[0 * R_RES + r] + qm_part[1 * R_RES + r] +
                         qm_part[2 * R_RES + r] + qm_part[3 * R_RES + r];

  if (tid < CIN) {
    float A = 0.f;
    #pragma unroll
    for (int ch = 0; ch < 4; ++ch)
      A += qpool_part[((size_t)ch * R_RES + r) * CIN + tid];
    s_qp[tid] = (ln_w[tid] * A + ln_b[tid] * msum_tot) / (msum_tot + 1e-10f);
  }
  __syncthreads();
  if (tid < HC) {
    float qj = 0.f;
    for (int c = 0; c < CIN; ++c) qj += s_qp[c] * wq[c * HC + tid];
    s_q[tid] = qj * 0.35355339059327373f;  // 1/sqrt(8)
  }
  __syncthreads();

  // ---- single online pass over S ----
  float mh[NH], dp[NH];
  #pragma unroll
  for (int h = 0; h < NH; ++h) { mh[h] = -1e30f; dp[h] = 0.f; }
  float opart[HC];
  #pragma unroll
  for (int i = 0; i < HC; ++i) opart[i] = 0.f;

  for (int s = tid; s < S_SEQ; s += 256) {
    float kk[CHD], vv[CHD];
    const float4* kp = reinterpret_cast<const float4*>(Kd + ((size_t)r * S_SEQ + s) * CHD);
    const float4* vp = reinterpret_cast<const float4*>(Vd + ((size_t)r * S_SEQ + s) * CHD);
    float4 a = kp[0], b = kp[1], c4 = vp[0], d4 = vp[1];
    kk[0] = a.x; kk[1] = a.y; kk[2] = a.z; kk[3] = a.w;
    kk[4] = b.x; kk[5] = b.y; kk[6] = b.z; kk[7] = b.w;
    vv[0] = c4.x; vv[1] = c4.y; vv[2] = c4.z; vv[3] = c4.w;
    vv[4] = d4.x; vv[5] = d4.y; vv[6] = d4.z; vv[7] = d4.w;
    const float madd = 1e9f * (maskT[(size_t)r * S_SEQ + s] - 1.0f);
    #pragma unroll
    for (int h = 0; h < NH; ++h) {
      float l = madd;
      #pragma unroll
      for (int j = 0; j < CHD; ++j) l += s_q[h * CHD + j] * kk[j];
      const float newm = fmaxf(mh[h], l);
      const float sc = __expf(mh[h] - newm);  // 1 if max unchanged
      const float p  = __expf(l - newm);
      dp[h] = dp[h] * sc + p;
      #pragma unroll
      for (int j = 0; j < CHD; ++j)
        opart[h * CHD + j] = opart[h * CHD + j] * sc + p * vv[j];
      mh[h] = newm;
    }
  }

  // ---- cross-lane/wave max ----
  float wm[NH];
  #pragma unroll
  for (int h = 0; h < NH; ++h) {
    wm[h] = mh[h];
    #pragma unroll
    for (int off = 32; off >= 1; off >>= 1)
      wm[h] = fmaxf(wm[h], __shfl_xor(wm[h], off, 64));
  }
  if (lane == 0) {
    #pragma unroll
    for (int h = 0; h < NH; ++h) mred[wave][h] = wm[h];
  }
  __syncthreads();
  #pragma unroll
  for (int h = 0; h < NH; ++h)
    wm[h] = fmaxf(fmaxf(mred[0][h], mred[1][h]), fmaxf(mred[2][h], mred[3][h]));

  // ---- rescale lane-local partials to global max (exact) ----
  #pragma unroll
  for (int h = 0; h < NH; ++h) {
    const float sc = __expf(mh[h] - wm[h]);
    dp[h] *= sc;
    #pragma unroll
    for (int j = 0; j < CHD; ++j) opart[h * CHD + j] *= sc;
  }

  // ---- reductions ----
  #pragma unroll
  for (int h = 0; h < NH; ++h) {
    float v = dp[h];
    #pragma unroll
    for (int off = 32; off >= 1; off >>= 1) v += __shfl_xor(v, off, 64);
    dp[h] = v;
  }
  if (lane == 0) {
    #pragma unroll
    for (int h = 0; h < NH; ++h) dred[wave][h] = dp[h];
  }
  float keep = 0.f;
  #pragma unroll
  for (int c = 0; c < HC; ++c) {
    float val = opart[c];
    #pragma unroll
    for (int off = 32; off >= 1; off >>= 1) val += __shfl_xor(val, off, 64);
    if (lane == c) keep = val;
  }
  redw[wave][lane] = keep;
  __syncthreads();
  if (tid < HC) {
    const float tot = redw[0][tid] + redw[1][tid] + redw[2][tid] + redw[3][tid];
    const int h = tid >> 3;
    const float den = dred[0][h] + dred[1][h] + dred[2][h] + dred[3][h];
    od[(size_t)r * HC + tid] = tot / den;
  }
}

// ---------------------------------------------------------------------------
// Kernel 3 (MFMA): EXACT round-9 kernel (measured 135 us). Do not edit.
// ---------------------------------------------------------------------------
__global__ __launch_bounds__(128) void k3_mfma(
    const float* __restrict__ m,
    const float* __restrict__ ln_w, const float* __restrict__ ln_b,
    const short* __restrict__ wgT_hi, const short* __restrict__ wgT_lo,
    const short* __restrict__ woT_hi, const short* __restrict__ woT_lo,
    const float* __restrict__ bg, const float* __restrict__ bo,
    const float* __restrict__ od, float* __restrict__ out) {
  const int tid = threadIdx.x;
  const int wave = tid >> 6;
  const int lane = tid & 63;
  const int lrow = lane & 15;   // A/B frag row index
  const int lpart = lane >> 4;  // 0..3, k-chunk owner
  const size_t base = (size_t)blockIdx.x * 128 + (size_t)wave * 64;
  const int base_r = (int)(base % R_RES);

  __shared__ float t_lds[2][64 * 64];  // per-wave t tile, XOR-swizzled rows
  float* tw = t_lds[wave];

  // per-lane bias values for columns j = n*16 + lrow
  float bgv[4], bov[4];
  #pragma unroll
  for (int n = 0; n < 4; ++n) { bgv[n] = bg[n * 16 + lrow]; bov[n] = bo[n * 16 + lrow]; }

  // LN params for this lane's two k-chunks: c = lpart*8+e and 32+lpart*8+e
  float lw0[8], lb0[8], lw1[8], lb1[8];
  {
    const float4* w0 = reinterpret_cast<const float4*>(ln_w + lpart * 8);
    const float4* w1 = reinterpret_cast<const float4*>(ln_w + 32 + lpart * 8);
    const float4* b0 = reinterpret_cast<const float4*>(ln_b + lpart * 8);
    const float4* b1 = reinterpret_cast<const float4*>(ln_b + 32 + lpart * 8);
    float4 a = w0[0], b = w0[1], c = w1[0], d = w1[1];
    lw0[0]=a.x; lw0[1]=a.y; lw0[2]=a.z; lw0[3]=a.w; lw0[4]=b.x; lw0[5]=b.y; lw0[6]=b.z; lw0[7]=b.w;
    lw1[0]=c.x; lw1[1]=c.y; lw1[2]=c.z; lw1[3]=c.w; lw1[4]=d.x; lw1[5]=d.y; lw1[6]=d.z; lw1[7]=d.w;
    a = b0[0]; b = b0[1]; c = b1[0]; d = b1[1];
    lb0[0]=a.x; lb0[1]=a.y; lb0[2]=a.z; lb0[3]=a.w; lb0[4]=b.x; lb0[5]=b.y; lb0[6]=b.z; lb0[7]=b.w;
    lb1[0]=c.x; lb1[1]=c.y; lb1[2]=c.z; lb1[3]=c.w; lb1[4]=d.x; lb1[5]=d.y; lb1[6]=d.z; lb1[7]=d.w;
  }

  // ---- B1 frags (wgT hi/lo): [n][k], lane reads wgT[n*16+lrow][k*32 + lpart*8 ..+7]
  bf16x8 b1h[4][2], b1l[4][2];
  #pragma unroll
  for (int n = 0; n < 4; ++n) {
    #pragma unroll
    for (int k = 0; k < 2; ++k) {
      const int idx = (n * 16 + lrow) * 64 + k * 32 + lpart * 8;
      b1h[n][k] = *reinterpret_cast<const bf16x8*>(wgT_hi + idx);
      b1l[n][k] = *reinterpret_cast<const bf16x8*>(wgT_lo + idx);
    }
  }

  // ---- Pass 1: LN -> GEMM1 -> sigmoid*o -> t to LDS ----
  #pragma unroll
  for (int mt = 0; mt < 4; ++mt) {
    const size_t grow = base + mt * 16 + lrow;
    const float* mrow = m + grow * CIN;
    float x0[8], x1[8];
    {
      const float4* p0 = reinterpret_cast<const float4*>(mrow + lpart * 8);
      const float4* p1 = reinterpret_cast<const float4*>(mrow + 32 + lpart * 8);
      float4 a = p0[0], b = p0[1], c = p1[0], d = p1[1];
      x0[0]=a.x; x0[1]=a.y; x0[2]=a.z; x0[3]=a.w; x0[4]=b.x; x0[5]=b.y; x0[6]=b.z; x0[7]=b.w;
      x1[0]=c.x; x1[1]=c.y; x1[2]=c.z; x1[3]=c.w; x1[4]=d.x; x1[5]=d.y; x1[6]=d.z; x1[7]=d.w;
    }
    float s = 0.f;
    #pragma unroll
    for (int e = 0; e < 8; ++e) s += x0[e] + x1[e];
    s += __shfl_xor(s, 16, 64);
    s += __shfl_xor(s, 32, 64);
    const float mean = s * (1.0f / CIN);
    float vs = 0.f;
    #pragma unroll
    for (int e = 0; e < 8; ++e) {
      float d0 = x0[e] - mean, d1 = x1[e] - mean;
      vs += d0 * d0 + d1 * d1;
    }
    vs += __shfl_xor(vs, 16, 64);
    vs += __shfl_xor(vs, 32, 64);
    const float rstd = rsqrtf(vs * (1.0f / CIN) + 1e-5f);

    bf16x8 ah0, al0, ah1, al1;
    #pragma unroll
    for (int e = 0; e < 8; ++e) {
      float xn = (x0[e] - mean) * rstd * lw0[e] + lb0[e];
      short h = f2bf(xn);
      ah0[e] = h; al0[e] = f2bf(xn - bf2f(h));
      xn = (x1[e] - mean) * rstd * lw1[e] + lb1[e];
      h = f2bf(xn);
      ah1[e] = h; al1[e] = f2bf(xn - bf2f(h));
    }

    #pragma unroll
    for (int n = 0; n < 4; ++n) {
      f32x4 acc = {0.f, 0.f, 0.f, 0.f};
      acc = __builtin_amdgcn_mfma_f32_16x16x32_bf16(ah0, b1h[n][0], acc, 0, 0, 0);
      acc = __builtin_amdgcn_mfma_f32_16x16x32_bf16(ah1, b1h[n][1], acc, 0, 0, 0);
      acc = __builtin_amdgcn_mfma_f32_16x16x32_bf16(ah0, b1l[n][0], acc, 0, 0, 0);
      acc = __builtin_amdgcn_mfma_f32_16x16x32_bf16(ah1, b1l[n][1], acc, 0, 0, 0);
      acc = __builtin_amdgcn_mfma_f32_16x16x32_bf16(al0, b1h[n][0], acc, 0, 0, 0);
      acc = __builtin_amdgcn_mfma_f32_16x16x32_bf16(al1, b1h[n][1], acc, 0, 0, 0);
      const int j = n * 16 + lrow;
      #pragma unroll
      for (int i = 0; i < 4; ++i) {
        const int rl = mt * 16 + lpart * 4 + i;
        int r = base_r + rl; if (r >= R_RES) r -= R_RES;
        const float z = acc[i] + bgv[n];
        const float g = 1.0f / (1.0f + __expf(-z));
        const float t = g * od[(size_t)r * HC + j];
        const int off = ((rl * 256 + j * 4)) ^ ((rl & 7) << 4);
        *reinterpret_cast<float*>(reinterpret_cast<char*>(tw) + off) = t;
      }
    }
  }

  __syncthreads();  // safe ordering of LDS writes -> reads (also within wave)

  // ---- B2 frags (woT hi/lo) replace B1 ----
  bf16x8 b2h[4][2], b2l[4][2];
  #pragma unroll
  for (int n = 0; n < 4; ++n) {
    #pragma unroll
    for (int k = 0; k < 2; ++k) {
      const int idx = (n * 16 + lrow) * 64 + k * 32 + lpart * 8;
      b2h[n][k] = *reinterpret_cast<const bf16x8*>(woT_hi + idx);
      b2l[n][k] = *reinterpret_cast<const bf16x8*>(woT_lo + idx);
    }
  }

  // ---- Pass 2: t -> GEMM2 -> out ----
  #pragma unroll
  for (int mt = 0; mt < 4; ++mt) {
    const int rl2 = mt * 16 + lrow;
    const int swz = (rl2 & 7) << 4;
    bf16x8 ah0, al0, ah1, al1;
    {
      const int a0 = rl2 * 256 + lpart * 32;         // k-chunk 0: j = lpart*8..
      const int a1 = rl2 * 256 + 128 + lpart * 32;   // k-chunk 1: j = 32+lpart*8..
      char* tb = reinterpret_cast<char*>(tw);
      float4 u0 = *reinterpret_cast<float4*>(tb + (a0 ^ swz));
      float4 u1 = *reinterpret_cast<float4*>(tb + ((a0 + 16) ^ swz));
      float4 u2 = *reinterpret_cast<float4*>(tb + (a1 ^ swz));
      float4 u3 = *reinterpret_cast<float4*>(tb + ((a1 + 16) ^ swz));
      float t0[8] = {u0.x, u0.y, u0.z, u0.w, u1.x, u1.y, u1.z, u1.w};
      float t1[8] = {u2.x, u2.y, u2.z, u2.w, u3.x, u3.y, u3.z, u3.w};
      #pragma unroll
      for (int e = 0; e < 8; ++e) {
        short h = f2bf(t0[e]);
        ah0[e] = h; al0[e] = f2bf(t0[e] - bf2f(h));
        h = f2bf(t1[e]);
        ah1[e] = h; al1[e] = f2bf(t1[e] - bf2f(h));
      }
    }
    #pragma unroll
    for (int n = 0; n < 4; ++n) {
      f32x4 acc = {0.f, 0.f, 0.f, 0.f};
      acc = __builtin_amdgcn_mfma_f32_16x16x32_bf16(ah0, b2h[n][0], acc, 0, 0, 0);
      acc = __builtin_amdgcn_mfma_f32_16x16x32_bf16(ah1, b2h[n][1], acc, 0, 0, 0);
      acc = __builtin_amdgcn_mfma_f32_16x16x32_bf16(ah0, b2l[n][0], acc, 0, 0, 0);
      acc = __builtin_amdgcn_mfma_f32_16x16x32_bf16(ah1, b2l[n][1], acc, 0, 0, 0);
      acc = __builtin_amdgcn_mfma_f32_16x16x32_bf16(al0, b2h[n][0], acc, 0, 0, 0);
      acc = __builtin_amdgcn_mfma_f32_16x16x32_bf16(al1, b2h[n][1], acc, 0, 0, 0);
      const int cc = n * 16 + lrow;
      #pragma unroll
      for (int i = 0; i < 4; ++i) {
        const size_t grow = base + mt * 16 + lpart * 4 + i;
        out[grow * CIN + cc] = acc[i] + bov[n];
      }
    }
  }
}

// ---------------------------------------------------------------------------
extern "C" void kernel_launch(void* const* d_in, const int* in_sizes, int n_in,
                              void* d_out, int out_size, void* d_ws, size_t ws_size,
                              hipStream_t stream) {
  const float* m    = (const float*)d_in[0];
  const float* mask = (const float*)d_in[1];
  const float* ln_w = (const float*)d_in[2];
  const float* ln_b = (const float*)d_in[3];
  const float* wq   = (const float*)d_in[4];
  const float* wk   = (const float*)d_in[5];
  const float* wv   = (const float*)d_in[6];
  const float* wg   = (const float*)d_in[7];
  const float* bg   = (const float*)d_in[8];
  const float* wo   = (const float*)d_in[9];
  const float* bo   = (const float*)d_in[10];
  float* out = (float*)d_out;

  const size_t sizeK   = (size_t)R_RES * S_SEQ * CHD * sizeof(float);   // 25.2 MB
  const size_t sizeQP  = (size_t)4 * R_RES * CIN * sizeof(float);       // 393 KB
  const size_t sizeQM  = (size_t)4 * R_RES * sizeof(float);
  const size_t sizeO   = (size_t)R_RES * HC * sizeof(float);
  const size_t sizeW   = (size_t)HC * CIN * sizeof(short);              // 8 KB
  const size_t sizeWKV = (size_t)16 * CIN * sizeof(short);              // 2 KB
  const size_t sizeMT  = (size_t)S_SEQ * R_RES * sizeof(float);         // 3.1 MB

  char* ws = (char*)d_ws;
  float* Kd         = (float*)(ws);
  float* Vd         = (float*)(ws + sizeK);
  float* qpool_part = (float*)(ws + 2 * sizeK);
  float* qm_part    = (float*)(ws + 2 * sizeK + sizeQP);
  float* od         = (float*)(ws + 2 * sizeK + sizeQP + sizeQM);
  char* wbase       = ws + 2 * sizeK + sizeQP + sizeQM + sizeO;
  short* wgT_hi  = (short*)(wbase);
  short* wgT_lo  = (short*)(wbase + sizeW);
  short* woT_hi  = (short*)(wbase + 2 * sizeW);
  short* woT_lo  = (short*)(wbase + 3 * sizeW);
  short* wkvT_hi = (short*)(wbase + 4 * sizeW);
  short* wkvT_lo = (short*)(wbase + 4 * sizeW + sizeWKV);
  float* bkv     = (float*)(wbase + 4 * sizeW + 2 * sizeWKV);
  float* maskT   = (float*)(wbase + 4 * sizeW + 2 * sizeWKV + 256);

  k0_prep<<<(HC * CIN + 255) / 256, 256, 0, stream>>>(
      wg, wo, wk, wv, ln_w, ln_b,
      wgT_hi, wgT_lo, woT_hi, woT_lo, wkvT_hi, wkvT_lo, bkv);

  k_mt<<<dim3(S_SEQ / 32, R_RES / 32), 256, 0, stream>>>(mask, maskT);

  k1_mfma<<<dim3(R_RES, 4), 256, 0, stream>>>(
      m, maskT, wkvT_hi, wkvT_lo, bkv, Kd, Vd, qpool_part, qm_part);

  k2_attn<<<R_RES, 256, 0, stream>>>(
      maskT, ln_w, ln_b, wq, qpool_part, qm_part, Kd, Vd, od);

  k3_mfma<<<(S_SEQ * R_RES) / 128, 128, 0, stream>>>(
      m, ln_w, ln_b, wgT_hi, wgT_lo, woT_hi, woT_lo, bg, bo, od, out);
}